// Round 1
// baseline (1333.900 us; speedup 1.0000x reference)
//
#include <hip/hip_runtime.h>
#include <math.h>

namespace {

constexpr int NL  = 1024;  // sequence length
constexpr int ND  = 512;   // model dim
constexpr int NH  = 8;     // heads
constexpr int NHD = 64;    // head dim
constexpr int NV3 = 36;    // 3*VD
constexpr int TOK = 8;     // tokens per block (projection / final kernels)
constexpr int QT  = 4;     // query rows per block (attention)

constexpr float SCL_S = 0.044194173824159216f; // 1/sqrt(512)
constexpr float SCL_V = 1.0f / 6.0f;           // 1/sqrt(36)

// ---------------------------------------------------------------- k_qkv
// q/k/v = x @ w_{q,k,v}; RoPE applied to q,k. Layout out: (B,H,L,64)
__global__ __launch_bounds__(256) void k_qkv(
    const float* __restrict__ x,
    const float* __restrict__ wq, const float* __restrict__ wk,
    const float* __restrict__ wv,
    float* __restrict__ q, float* __restrict__ k, float* __restrict__ v)
{
  __shared__ float xs[TOK][ND];
  __shared__ float qs[TOK][ND];
  __shared__ float ks[TOK][ND];
  const int tb  = blockIdx.x * TOK;
  const int b   = tb >> 10;
  const int l0  = tb & (NL - 1);
  const int tid = threadIdx.x;

  for (int i = tid; i < TOK * ND; i += 256)
    xs[i >> 9][i & (ND - 1)] = x[(size_t)tb * ND + i];
  __syncthreads();

  for (int n = tid; n < ND; n += 256) {
    float aq[TOK], ak[TOK], av[TOK];
#pragma unroll
    for (int t = 0; t < TOK; ++t) { aq[t] = 0.f; ak[t] = 0.f; av[t] = 0.f; }
    for (int d = 0; d < ND; ++d) {
      const float w0 = wq[d * ND + n];
      const float w1 = wk[d * ND + n];
      const float w2 = wv[d * ND + n];
#pragma unroll
      for (int t = 0; t < TOK; ++t) {
        const float xv = xs[t][d];
        aq[t] = fmaf(xv, w0, aq[t]);
        ak[t] = fmaf(xv, w1, ak[t]);
        av[t] = fmaf(xv, w2, av[t]);
      }
    }
    const int h = n >> 6, hd = n & 63;
#pragma unroll
    for (int t = 0; t < TOK; ++t) {
      qs[t][n] = aq[t];
      ks[t][n] = ak[t];
      v[((size_t)(b * NH + h) * NL + l0 + t) * NHD + hd] = av[t];
    }
  }
  __syncthreads();

  for (int n = tid; n < ND; n += 256) {
    const int h = n >> 6, hd = n & 63;
    const int i2 = hd >> 1;
    const float inv = powf(10000.0f, -(float)(2 * i2) / 64.0f);
    const int base = n & ~1;
    const bool odd = (hd & 1) != 0;
#pragma unroll
    for (int t = 0; t < TOK; ++t) {
      float sv, cv;
      __sincosf((float)(l0 + t) * inv, &sv, &cv);
      const float qe = qs[t][base], qo = qs[t][base + 1];
      const float ke = ks[t][base], ko = ks[t][base + 1];
      const float qv = odd ? fmaf(qe, sv, qo * cv) : fmaf(qe, cv, -qo * sv);
      const float kv = odd ? fmaf(ke, sv, ko * cv) : fmaf(ke, cv, -ko * sv);
      const size_t idx = ((size_t)(b * NH + h) * NL + l0 + t) * NHD + hd;
      q[idx] = qv;
      k[idx] = kv;
    }
  }
}

// ---------------------------------------------------------------- k_proj
// vq/vk/vv = rot( x@w + b ) head-major (B,H,L,36); aq/av = rot(x@w+b)+trans (B,H,L,3)
__global__ __launch_bounds__(256) void k_proj(
    const float* __restrict__ x, const float* __restrict__ rots,
    const float* __restrict__ trans,
    const float* __restrict__ wvq, const float* __restrict__ bvq,
    const float* __restrict__ wvk, const float* __restrict__ bvk,
    const float* __restrict__ wvv, const float* __restrict__ bvv,
    const float* __restrict__ waq, const float* __restrict__ baq,
    const float* __restrict__ wav, const float* __restrict__ bav,
    float* __restrict__ vq, float* __restrict__ vk, float* __restrict__ vv,
    float* __restrict__ aq, float* __restrict__ av)
{
  __shared__ float xs[TOK][ND];
  __shared__ float rq[TOK][288], rk[TOK][288], rv[TOK][288];
  __shared__ float ra[TOK][24], rb[TOK][24];
  const int tb  = blockIdx.x * TOK;
  const int b   = tb >> 10;
  const int tid = threadIdx.x;

  for (int i = tid; i < TOK * ND; i += 256)
    xs[i >> 9][i & (ND - 1)] = x[(size_t)tb * ND + i];
  __syncthreads();

  for (int n = tid; n < 288; n += 256) {
    float a0[TOK], a1[TOK], a2[TOK];
#pragma unroll
    for (int t = 0; t < TOK; ++t) { a0[t] = bvq[n]; a1[t] = bvk[n]; a2[t] = bvv[n]; }
    for (int d = 0; d < ND; ++d) {
      const float w0 = wvq[d * 288 + n];
      const float w1 = wvk[d * 288 + n];
      const float w2 = wvv[d * 288 + n];
#pragma unroll
      for (int t = 0; t < TOK; ++t) {
        const float xv = xs[t][d];
        a0[t] = fmaf(xv, w0, a0[t]);
        a1[t] = fmaf(xv, w1, a1[t]);
        a2[t] = fmaf(xv, w2, a2[t]);
      }
    }
#pragma unroll
    for (int t = 0; t < TOK; ++t) { rq[t][n] = a0[t]; rk[t][n] = a1[t]; rv[t][n] = a2[t]; }
  }
  if (tid < 24) {
    const int n = tid;
    float a0[TOK], a1[TOK];
#pragma unroll
    for (int t = 0; t < TOK; ++t) { a0[t] = baq[n]; a1[t] = bav[n]; }
    for (int d = 0; d < ND; ++d) {
      const float w0 = waq[d * 24 + n];
      const float w1 = wav[d * 24 + n];
#pragma unroll
      for (int t = 0; t < TOK; ++t) {
        const float xv = xs[t][d];
        a0[t] = fmaf(xv, w0, a0[t]);
        a1[t] = fmaf(xv, w1, a1[t]);
      }
    }
#pragma unroll
    for (int t = 0; t < TOK; ++t) { ra[t][n] = a0[t]; rb[t][n] = a1[t]; }
  }
  __syncthreads();

  // rotate the 288-wide projections: out_d = sum_c R[d][c] * raw_c
  for (int u = tid; u < TOK * 288; u += 256) {
    const int t = u / 288, n = u % 288;
    const int l = tb + t;
    const int ll = l & (NL - 1);
    const int c = n % 3;               // output component d
    const int base = n - c;            // h*36 + v*3
    const float r0 = rots[(size_t)l * 9 + c * 3 + 0];
    const float r1 = rots[(size_t)l * 9 + c * 3 + 1];
    const float r2 = rots[(size_t)l * 9 + c * 3 + 2];
    const int h = n / NV3;
    const size_t ob = ((size_t)(b * NH + h) * NL + ll) * NV3 + (n % NV3);
    vq[ob] = r0 * rq[t][base] + r1 * rq[t][base + 1] + r2 * rq[t][base + 2];
    vk[ob] = r0 * rk[t][base] + r1 * rk[t][base + 1] + r2 * rk[t][base + 2];
    vv[ob] = r0 * rv[t][base] + r1 * rv[t][base + 1] + r2 * rv[t][base + 2];
  }
  for (int u = tid; u < TOK * 24; u += 256) {
    const int t = u / 24, n = u % 24;
    const int l = tb + t;
    const int ll = l & (NL - 1);
    const int c = n % 3;
    const int h = n / 3;
    const int base = h * 3;
    const float r0 = rots[(size_t)l * 9 + c * 3 + 0];
    const float r1 = rots[(size_t)l * 9 + c * 3 + 1];
    const float r2 = rots[(size_t)l * 9 + c * 3 + 2];
    const float tr = trans[(size_t)l * 3 + c];
    const size_t ob = ((size_t)(b * NH + h) * NL + ll) * 3 + c;
    aq[ob] = r0 * ra[t][base] + r1 * ra[t][base + 1] + r2 * ra[t][base + 2] + tr;
    av[ob] = r0 * rb[t][base] + r1 * rb[t][base + 1] + r2 * rb[t][base + 2] + tr;
  }
}

// ---------------------------------------------------------------- k_attn
__global__ __launch_bounds__(256) void k_attn(
    const float* __restrict__ q, const float* __restrict__ k,
    const float* __restrict__ v, const float* __restrict__ vq,
    const float* __restrict__ vk, const float* __restrict__ vv,
    const float* __restrict__ aqp, const float* __restrict__ avp,
    const float* __restrict__ mask, const float* __restrict__ trans,
    const float* __restrict__ rots, const float* __restrict__ affine_w,
    float* __restrict__ sc, float* __restrict__ vec, float* __restrict__ aff)
{
  __shared__ float p[QT][NL];
  __shared__ float qs[QT][NHD];
  __shared__ float vqs[QT][NV3];
  __shared__ float aqs[QT][3];
  __shared__ float vacc[QT][NV3];
  __shared__ float aacc[QT][3];

  const int blk = blockIdx.x;
  const int bh  = blk >> 8;           // 0..15
  const int i0  = (blk & 255) * QT;
  const int b   = bh >> 3, h = bh & 7;
  const int tid = threadIdx.x;

  for (int u = tid; u < QT * NHD; u += 256) {
    const int t = u >> 6, d = u & 63;
    qs[t][d] = q[((size_t)bh * NL + i0 + t) * NHD + d] * SCL_S;
  }
  for (int u = tid; u < QT * NV3; u += 256) {
    const int t = u / NV3, d = u % NV3;
    vqs[t][d] = vq[((size_t)bh * NL + i0 + t) * NV3 + d] * SCL_V;
  }
  if (tid < QT * 3) {
    const int t = tid / 3, d = tid % 3;
    aqs[t][d] = aqp[((size_t)bh * NL + i0 + t) * 3 + d];
  }
  __syncthreads();

  const float spw = logf(1.0f + expf(affine_w[h]));

  // phase 1: logits
  for (int j = tid; j < NL; j += 256) {
    const float* kr = k + ((size_t)bh * NL + j) * NHD;
    float s0 = 0.f, s1 = 0.f, s2 = 0.f, s3 = 0.f;
#pragma unroll 8
    for (int d = 0; d < NHD; ++d) {
      const float kv = kr[d];
      s0 = fmaf(qs[0][d], kv, s0);
      s1 = fmaf(qs[1][d], kv, s1);
      s2 = fmaf(qs[2][d], kv, s2);
      s3 = fmaf(qs[3][d], kv, s3);
    }
    const float* vkr = vk + ((size_t)bh * NL + j) * NV3;
#pragma unroll 6
    for (int d = 0; d < NV3; ++d) {
      const float kv = vkr[d];
      s0 = fmaf(vqs[0][d], kv, s0);
      s1 = fmaf(vqs[1][d], kv, s1);
      s2 = fmaf(vqs[2][d], kv, s2);
      s3 = fmaf(vqs[3][d], kv, s3);
    }
    const float* ar = aqp + ((size_t)bh * NL + j) * 3;
    const float a0 = ar[0], a1 = ar[1], a2 = ar[2];
    const float pen = 1e6f * (1.0f - mask[(size_t)b * NL + j]);
    {
      const float dx = aqs[0][0] - a0, dy = aqs[0][1] - a1, dz = aqs[0][2] - a2;
      s0 -= spw * sqrtf(dx * dx + dy * dy + dz * dz) + pen;
    }
    {
      const float dx = aqs[1][0] - a0, dy = aqs[1][1] - a1, dz = aqs[1][2] - a2;
      s1 -= spw * sqrtf(dx * dx + dy * dy + dz * dz) + pen;
    }
    {
      const float dx = aqs[2][0] - a0, dy = aqs[2][1] - a1, dz = aqs[2][2] - a2;
      s2 -= spw * sqrtf(dx * dx + dy * dy + dz * dz) + pen;
    }
    {
      const float dx = aqs[3][0] - a0, dy = aqs[3][1] - a1, dz = aqs[3][2] - a2;
      s3 -= spw * sqrtf(dx * dx + dy * dy + dz * dz) + pen;
    }
    p[0][j] = s0; p[1][j] = s1; p[2][j] = s2; p[3][j] = s3;
  }
  __syncthreads();

  // phase 2: softmax, one wave per query row
  {
    const int r = tid >> 6, lane = tid & 63;
    float m = -1e30f;
    for (int j = lane; j < NL; j += 64) m = fmaxf(m, p[r][j]);
#pragma unroll
    for (int off = 32; off; off >>= 1) m = fmaxf(m, __shfl_xor(m, off));
    float s = 0.f;
    for (int j = lane; j < NL; j += 64) {
      const float e = __expf(p[r][j] - m);
      p[r][j] = e;
      s += e;
    }
#pragma unroll
    for (int off = 32; off; off >>= 1) s += __shfl_xor(s, off);
    const float invs = 1.0f / s;
    for (int j = lane; j < NL; j += 64) p[r][j] *= invs;
  }
  __syncthreads();

  // phase 3: weighted sums — 4 rows x 103 dims (64 scalar, 36 vector, 3 affine)
  for (int task = tid; task < QT * 103; task += 256) {
    const int r = task / 103, dim = task % 103;
    const float* src;
    int stride;
    if (dim < 64)       { src = v   + (size_t)bh * NL * NHD + dim;         stride = NHD; }
    else if (dim < 100) { src = vv  + (size_t)bh * NL * NV3 + (dim - 64);  stride = NV3; }
    else                { src = avp + (size_t)bh * NL * 3   + (dim - 100); stride = 3; }
    const float* pr = p[r];
    float acc = 0.f;
#pragma unroll 4
    for (int j = 0; j < NL; ++j) acc = fmaf(pr[j], src[(size_t)j * stride], acc);
    const int i = i0 + r;
    if (dim < 64)       sc[((size_t)b * NL + i) * ND + h * NHD + dim] = acc;
    else if (dim < 100) vacc[r][dim - 64] = acc;
    else                aacc[r][dim - 100] = acc;
  }
  __syncthreads();

  // phase 4: output-side rotation (R^T), affine gets -trans first
  for (int u = tid; u < QT * 39; u += 256) {
    const int r = u / 39, w39 = u % 39;
    const size_t l = (size_t)b * NL + i0 + r;
    const float* R = rots + l * 9;
    if (w39 < NV3) {
      const int n = w39 % 3;
      const int base = w39 - n;
      const float val = vacc[r][base]     * R[0 * 3 + n]
                      + vacc[r][base + 1] * R[1 * 3 + n]
                      + vacc[r][base + 2] * R[2 * 3 + n];
      vec[l * 288 + h * NV3 + w39] = val;
    } else {
      const int n = w39 - NV3;
      const float c0 = aacc[r][0] - trans[l * 3 + 0];
      const float c1 = aacc[r][1] - trans[l * 3 + 1];
      const float c2 = aacc[r][2] - trans[l * 3 + 2];
      const float val = c0 * R[0 * 3 + n] + c1 * R[1 * 3 + n] + c2 * R[2 * 3 + n];
      aff[l * 24 + h * 3 + n] = val;
    }
  }
}

// ---------------------------------------------------------------- k_final
__global__ __launch_bounds__(256) void k_final(
    const float* __restrict__ sc, const float* __restrict__ vec,
    const float* __restrict__ aff,
    const float* __restrict__ w_o, const float* __restrict__ w_vo,
    const float* __restrict__ b_vo, const float* __restrict__ w_ao,
    const float* __restrict__ b_ao, float* __restrict__ out)
{
  __shared__ float scs[TOK][ND];
  __shared__ float vcs[TOK][288];
  __shared__ float afs[TOK][24];
  const int tb  = blockIdx.x * TOK;
  const int tid = threadIdx.x;

  for (int i = tid; i < TOK * ND; i += 256)
    scs[i >> 9][i & (ND - 1)] = sc[(size_t)tb * ND + i];
  for (int i = tid; i < TOK * 288; i += 256)
    vcs[i / 288][i % 288] = vec[(size_t)tb * 288 + i];
  for (int i = tid; i < TOK * 24; i += 256)
    afs[i / 24][i % 24] = aff[(size_t)tb * 24 + i];
  __syncthreads();

  for (int n = tid; n < ND; n += 256) {
    float a[TOK];
    const float bias = b_vo[n] + b_ao[n];
#pragma unroll
    for (int t = 0; t < TOK; ++t) a[t] = bias;
    for (int d = 0; d < ND; ++d) {
      const float wv = w_o[d * ND + n];
#pragma unroll
      for (int t = 0; t < TOK; ++t) a[t] = fmaf(scs[t][d], wv, a[t]);
    }
    for (int m = 0; m < 288; ++m) {
      const float wv = w_vo[m * ND + n];
#pragma unroll
      for (int t = 0; t < TOK; ++t) a[t] = fmaf(vcs[t][m], wv, a[t]);
    }
    for (int m = 0; m < 24; ++m) {
      const float wv = w_ao[m * ND + n];
#pragma unroll
      for (int t = 0; t < TOK; ++t) a[t] = fmaf(afs[t][m], wv, a[t]);
    }
#pragma unroll
    for (int t = 0; t < TOK; ++t) out[(size_t)(tb + t) * ND + n] = a[t];
  }
}

} // namespace

extern "C" void kernel_launch(void* const* d_in, const int* in_sizes, int n_in,
                              void* d_out, int out_size, void* d_ws, size_t ws_size,
                              hipStream_t stream)
{
  const float* x       = (const float*)d_in[0];
  const float* mask    = (const float*)d_in[1];
  const float* rots    = (const float*)d_in[2];
  const float* trans   = (const float*)d_in[3];
  const float* w_q     = (const float*)d_in[4];
  const float* w_k     = (const float*)d_in[5];
  const float* w_v     = (const float*)d_in[6];
  const float* w_o     = (const float*)d_in[7];
  const float* w_vq_w  = (const float*)d_in[8];
  const float* w_vq_b  = (const float*)d_in[9];
  const float* w_vk_w  = (const float*)d_in[10];
  const float* w_vk_b  = (const float*)d_in[11];
  const float* w_vv_w  = (const float*)d_in[12];
  const float* w_vv_b  = (const float*)d_in[13];
  const float* w_vo_w  = (const float*)d_in[14];
  const float* w_vo_b  = (const float*)d_in[15];
  const float* w_aq_w  = (const float*)d_in[16];
  const float* w_aq_b  = (const float*)d_in[17];
  const float* w_av_w  = (const float*)d_in[18];
  const float* w_av_b  = (const float*)d_in[19];
  const float* w_ao_w  = (const float*)d_in[20];
  const float* w_ao_b  = (const float*)d_in[21];
  const float* aff_w   = (const float*)d_in[22];
  float* out = (float*)d_out;

  // workspace layout (floats) — total 6,701,056 floats = 26.8 MB
  float* ws = (float*)d_ws;
  constexpr size_t SZ_Q   = (size_t)2 * 8 * 1024 * 64;  // 1048576
  constexpr size_t SZ_V36 = (size_t)2 * 8 * 1024 * 36;  // 589824
  constexpr size_t SZ_A3  = (size_t)2 * 8 * 1024 * 3;   // 49152
  float* q   = ws;
  float* k   = q  + SZ_Q;
  float* v   = k  + SZ_Q;
  float* vq  = v  + SZ_Q;
  float* vk  = vq + SZ_V36;
  float* vv  = vk + SZ_V36;
  float* aqp = vv + SZ_V36;
  float* avp = aqp + SZ_A3;
  float* sc  = avp + SZ_A3;                       // (B,L,512)
  float* vec = sc  + (size_t)2 * 1024 * 512;      // (B,L,288)
  float* aff = vec + (size_t)2 * 1024 * 288;      // (B,L,24)

  k_qkv<<<2048 / TOK, 256, 0, stream>>>(x, w_q, w_k, w_v, q, k, v);
  k_proj<<<2048 / TOK, 256, 0, stream>>>(x, rots, trans,
                                         w_vq_w, w_vq_b, w_vk_w, w_vk_b,
                                         w_vv_w, w_vv_b, w_aq_w, w_aq_b,
                                         w_av_w, w_av_b, vq, vk, vv, aqp, avp);
  k_attn<<<2 * 8 * (1024 / QT), 256, 0, stream>>>(q, k, v, vq, vk, vv, aqp, avp,
                                                  mask, trans, rots, aff_w,
                                                  sc, vec, aff);
  k_final<<<2048 / TOK, 256, 0, stream>>>(sc, vec, aff, w_o, w_vo_w, w_vo_b,
                                          w_ao_w, w_ao_b, out);
}

// Round 2
// 887.233 us; speedup vs baseline: 1.5034x; 1.5034x over previous
//
#include <hip/hip_runtime.h>
#include <math.h>

namespace {

constexpr int NL  = 1024;  // sequence length
constexpr int ND  = 512;   // model dim
constexpr int NH  = 8;     // heads
constexpr int NHD = 64;    // head dim
constexpr int NV3 = 36;    // 3*VD
constexpr int TOK = 8;     // tokens per block (projection / final kernels)
constexpr int QT  = 8;     // query rows per block (attention)

constexpr float SCL_S = 0.044194173824159216f; // 1/sqrt(512)
constexpr float SCL_V = 1.0f / 6.0f;           // 1/sqrt(36)

// ---------------------------------------------------------------- k_qkv
// q = rope(x@wq) layout (B,H,L,64); k_t = rope(x@wk) layout (B,H,64,L);
// v = x@wv layout (B,H,L,64)
__global__ __launch_bounds__(256) void k_qkv(
    const float* __restrict__ x,
    const float* __restrict__ wq, const float* __restrict__ wk,
    const float* __restrict__ wv,
    float* __restrict__ q, float* __restrict__ k_t, float* __restrict__ v)
{
  __shared__ float xs[TOK][ND];
  __shared__ float qs[TOK][ND];
  __shared__ float ks[TOK][ND];
  const int tb  = blockIdx.x * TOK;
  const int b   = tb >> 10;
  const int l0  = tb & (NL - 1);
  const int tid = threadIdx.x;

  for (int i = tid; i < TOK * ND; i += 256)
    xs[i >> 9][i & (ND - 1)] = x[(size_t)tb * ND + i];
  __syncthreads();

  for (int n = tid; n < ND; n += 256) {
    float aq[TOK], ak[TOK], av[TOK];
#pragma unroll
    for (int t = 0; t < TOK; ++t) { aq[t] = 0.f; ak[t] = 0.f; av[t] = 0.f; }
    for (int d = 0; d < ND; ++d) {
      const float w0 = wq[d * ND + n];
      const float w1 = wk[d * ND + n];
      const float w2 = wv[d * ND + n];
#pragma unroll
      for (int t = 0; t < TOK; ++t) {
        const float xv = xs[t][d];
        aq[t] = fmaf(xv, w0, aq[t]);
        ak[t] = fmaf(xv, w1, ak[t]);
        av[t] = fmaf(xv, w2, av[t]);
      }
    }
    const int h = n >> 6, hd = n & 63;
#pragma unroll
    for (int t = 0; t < TOK; ++t) {
      qs[t][n] = aq[t];
      ks[t][n] = ak[t];
      v[((size_t)(b * NH + h) * NL + l0 + t) * NHD + hd] = av[t];
    }
  }
  __syncthreads();

  for (int n = tid; n < ND; n += 256) {
    const int h = n >> 6, hd = n & 63;
    const float inv = powf(10000.0f, -(float)(hd & ~1) / 64.0f);
    const int base = n & ~1;
    const bool odd = (hd & 1) != 0;
    float qo[TOK], ko[TOK];
#pragma unroll
    for (int t = 0; t < TOK; ++t) {
      float sv, cv;
      __sincosf((float)(l0 + t) * inv, &sv, &cv);
      const float qe = qs[t][base], qon = qs[t][base + 1];
      const float ke = ks[t][base], kon = ks[t][base + 1];
      qo[t] = odd ? fmaf(qe, sv, qon * cv) : fmaf(qe, cv, -qon * sv);
      ko[t] = odd ? fmaf(ke, sv, kon * cv) : fmaf(ke, cv, -kon * sv);
    }
    // q: (bh, L, 64) — per-t coalesced across lanes
#pragma unroll
    for (int t = 0; t < TOK; ++t)
      q[((size_t)(b * NH + h) * NL + l0 + t) * NHD + hd] = qo[t];
    // k_t: (bh, 64, L) — 8 consecutive floats per thread
    const size_t row = ((size_t)(b * NH + h) * NHD + hd) * NL + l0;
    *(float4*)&k_t[row]     = make_float4(ko[0], ko[1], ko[2], ko[3]);
    *(float4*)&k_t[row + 4] = make_float4(ko[4], ko[5], ko[6], ko[7]);
  }
}

// ---------------------------------------------------------------- k_proj
// vq/vv = rot(x@w+b) layout (B,H,L,36); vk_t = rot(x@w+b) layout (B,H,36,L)
// aq_t = rot(x@w+b)+trans layout (B,H,3,L); av = same, layout (B,H,L,3)
__global__ __launch_bounds__(256) void k_proj(
    const float* __restrict__ x, const float* __restrict__ rots,
    const float* __restrict__ trans,
    const float* __restrict__ wvq, const float* __restrict__ bvq,
    const float* __restrict__ wvk, const float* __restrict__ bvk,
    const float* __restrict__ wvv, const float* __restrict__ bvv,
    const float* __restrict__ waq, const float* __restrict__ baq,
    const float* __restrict__ wav, const float* __restrict__ bav,
    float* __restrict__ vq, float* __restrict__ vk_t, float* __restrict__ vv,
    float* __restrict__ aq_t, float* __restrict__ av)
{
  __shared__ float xs[TOK][ND];
  __shared__ float rq[TOK][288], rk[TOK][288], rv[TOK][288];
  __shared__ float ra[TOK][24], rb[TOK][24];
  const int tb  = blockIdx.x * TOK;
  const int b   = tb >> 10;
  const int tid = threadIdx.x;

  for (int i = tid; i < TOK * ND; i += 256)
    xs[i >> 9][i & (ND - 1)] = x[(size_t)tb * ND + i];
  __syncthreads();

  for (int n = tid; n < 288; n += 256) {
    float a0[TOK], a1[TOK], a2[TOK];
#pragma unroll
    for (int t = 0; t < TOK; ++t) { a0[t] = bvq[n]; a1[t] = bvk[n]; a2[t] = bvv[n]; }
    for (int d = 0; d < ND; ++d) {
      const float w0 = wvq[d * 288 + n];
      const float w1 = wvk[d * 288 + n];
      const float w2 = wvv[d * 288 + n];
#pragma unroll
      for (int t = 0; t < TOK; ++t) {
        const float xv = xs[t][d];
        a0[t] = fmaf(xv, w0, a0[t]);
        a1[t] = fmaf(xv, w1, a1[t]);
        a2[t] = fmaf(xv, w2, a2[t]);
      }
    }
#pragma unroll
    for (int t = 0; t < TOK; ++t) { rq[t][n] = a0[t]; rk[t][n] = a1[t]; rv[t][n] = a2[t]; }
  }
  if (tid < 24) {
    const int n = tid;
    float a0[TOK], a1[TOK];
#pragma unroll
    for (int t = 0; t < TOK; ++t) { a0[t] = baq[n]; a1[t] = bav[n]; }
    for (int d = 0; d < ND; ++d) {
      const float w0 = waq[d * 24 + n];
      const float w1 = wav[d * 24 + n];
#pragma unroll
      for (int t = 0; t < TOK; ++t) {
        const float xv = xs[t][d];
        a0[t] = fmaf(xv, w0, a0[t]);
        a1[t] = fmaf(xv, w1, a1[t]);
      }
    }
#pragma unroll
    for (int t = 0; t < TOK; ++t) { ra[t][n] = a0[t]; rb[t][n] = a1[t]; }
  }
  __syncthreads();

  // loop A: vq, vv in (bh, L, 36) layout — n fastest across lanes (coalesced)
  for (int u = tid; u < TOK * 288; u += 256) {
    const int t = u / 288, n = u % 288;
    const int l = tb + t;
    const int ll = l & (NL - 1);
    const int c = n % 3;
    const int base = n - c;
    const float r0 = rots[(size_t)l * 9 + c * 3 + 0];
    const float r1 = rots[(size_t)l * 9 + c * 3 + 1];
    const float r2 = rots[(size_t)l * 9 + c * 3 + 2];
    const int h = n / NV3;
    const size_t ob = ((size_t)(b * NH + h) * NL + ll) * NV3 + (n % NV3);
    vq[ob] = r0 * rq[t][base] + r1 * rq[t][base + 1] + r2 * rq[t][base + 2];
    vv[ob] = r0 * rv[t][base] + r1 * rv[t][base + 1] + r2 * rv[t][base + 2];
  }
  // loop B: vk_t in (bh, 36, L) layout — t fastest across lanes (8-runs)
  for (int u = tid; u < TOK * 288; u += 256) {
    const int t = u & 7, n = u >> 3;
    const int l = tb + t;
    const int ll = l & (NL - 1);
    const int c = n % 3;
    const int base = n - c;
    const float r0 = rots[(size_t)l * 9 + c * 3 + 0];
    const float r1 = rots[(size_t)l * 9 + c * 3 + 1];
    const float r2 = rots[(size_t)l * 9 + c * 3 + 2];
    const int h = n / NV3, m = n % NV3;
    vk_t[((size_t)(b * NH + h) * NV3 + m) * NL + ll] =
        r0 * rk[t][base] + r1 * rk[t][base + 1] + r2 * rk[t][base + 2];
  }
  // aq_t (bh,3,L), t fastest
  for (int u = tid; u < TOK * 24; u += 256) {
    const int t = u & 7, n = u >> 3;  // n = h*3 + c
    const int l = tb + t;
    const int ll = l & (NL - 1);
    const int c = n % 3, h = n / 3;
    const int base = h * 3;
    const float r0 = rots[(size_t)l * 9 + c * 3 + 0];
    const float r1 = rots[(size_t)l * 9 + c * 3 + 1];
    const float r2 = rots[(size_t)l * 9 + c * 3 + 2];
    const float tr = trans[(size_t)l * 3 + c];
    aq_t[((size_t)(b * NH + h) * 3 + c) * NL + ll] =
        r0 * ra[t][base] + r1 * ra[t][base + 1] + r2 * ra[t][base + 2] + tr;
  }
  // av (bh,L,3), n fastest
  for (int u = tid; u < TOK * 24; u += 256) {
    const int t = u / 24, n = u % 24;
    const int l = tb + t;
    const int ll = l & (NL - 1);
    const int c = n % 3, h = n / 3;
    const int base = h * 3;
    const float r0 = rots[(size_t)l * 9 + c * 3 + 0];
    const float r1 = rots[(size_t)l * 9 + c * 3 + 1];
    const float r2 = rots[(size_t)l * 9 + c * 3 + 2];
    const float tr = trans[(size_t)l * 3 + c];
    av[((size_t)(b * NH + h) * NL + ll) * 3 + c] =
        r0 * rb[t][base] + r1 * rb[t][base + 1] + r2 * rb[t][base + 2] + tr;
  }
}

// ---------------------------------------------------------------- k_attn
__global__ __launch_bounds__(256) void k_attn(
    const float* __restrict__ q, const float* __restrict__ k_t,
    const float* __restrict__ v, const float* __restrict__ vq,
    const float* __restrict__ vk_t, const float* __restrict__ vv,
    const float* __restrict__ aq_t, const float* __restrict__ avp,
    const float* __restrict__ mask, const float* __restrict__ trans,
    const float* __restrict__ rots, const float* __restrict__ affine_w,
    float* __restrict__ sc, float* __restrict__ vec, float* __restrict__ aff)
{
  __shared__ float pt[NL][QT];    // [j][r] — r contiguous for b128 reads
  __shared__ float qs[NHD][QT];   // [d][r]
  __shared__ float vqs[NV3][QT];
  __shared__ float aqs[3][QT];
  __shared__ float vacc[QT][NV3];
  __shared__ float aacc[QT][3];
  __shared__ float rinv[QT];

  const int blk = blockIdx.x;
  const int bh  = blk >> 7;            // 0..15
  const int i0  = (blk & 127) * QT;
  const int b   = bh >> 3, h = bh & 7;
  const int tid = threadIdx.x;

  for (int u = tid; u < NHD * QT; u += 256) {
    const int d = u >> 3, t = u & 7;
    qs[d][t] = q[((size_t)bh * NL + i0 + t) * NHD + d] * SCL_S;
  }
  for (int u = tid; u < NV3 * QT; u += 256) {
    const int d = u >> 3, t = u & 7;
    vqs[d][t] = vq[((size_t)bh * NL + i0 + t) * NV3 + d] * SCL_V;
  }
  if (tid < 3 * QT) {
    const int d = tid >> 3, t = tid & 7;
    aqs[d][t] = aq_t[((size_t)bh * 3 + d) * NL + i0 + t];
  }
  __syncthreads();

  const float spw = logf(1.0f + expf(affine_w[h]));

  // phase 1: logits — thread owns columns j = tid + 256*qq, qq=0..3
  {
    float s[4][QT];
#pragma unroll
    for (int qq = 0; qq < 4; ++qq)
#pragma unroll
      for (int t = 0; t < QT; ++t) s[qq][t] = 0.f;

    const float* kt = k_t + (size_t)bh * NHD * NL + tid;
    for (int d = 0; d < NHD; ++d) {
      const float4 qa = *(const float4*)&qs[d][0];
      const float4 qb = *(const float4*)&qs[d][4];
#pragma unroll
      for (int qq = 0; qq < 4; ++qq) {
        const float kv = kt[(size_t)d * NL + qq * 256];
        s[qq][0] = fmaf(qa.x, kv, s[qq][0]);
        s[qq][1] = fmaf(qa.y, kv, s[qq][1]);
        s[qq][2] = fmaf(qa.z, kv, s[qq][2]);
        s[qq][3] = fmaf(qa.w, kv, s[qq][3]);
        s[qq][4] = fmaf(qb.x, kv, s[qq][4]);
        s[qq][5] = fmaf(qb.y, kv, s[qq][5]);
        s[qq][6] = fmaf(qb.z, kv, s[qq][6]);
        s[qq][7] = fmaf(qb.w, kv, s[qq][7]);
      }
    }
    const float* vkt = vk_t + (size_t)bh * NV3 * NL + tid;
    for (int d = 0; d < NV3; ++d) {
      const float4 qa = *(const float4*)&vqs[d][0];
      const float4 qb = *(const float4*)&vqs[d][4];
#pragma unroll
      for (int qq = 0; qq < 4; ++qq) {
        const float kv = vkt[(size_t)d * NL + qq * 256];
        s[qq][0] = fmaf(qa.x, kv, s[qq][0]);
        s[qq][1] = fmaf(qa.y, kv, s[qq][1]);
        s[qq][2] = fmaf(qa.z, kv, s[qq][2]);
        s[qq][3] = fmaf(qa.w, kv, s[qq][3]);
        s[qq][4] = fmaf(qb.x, kv, s[qq][4]);
        s[qq][5] = fmaf(qb.y, kv, s[qq][5]);
        s[qq][6] = fmaf(qb.z, kv, s[qq][6]);
        s[qq][7] = fmaf(qb.w, kv, s[qq][7]);
      }
    }
    const float* aqt = aq_t + (size_t)bh * 3 * NL + tid;
#pragma unroll
    for (int qq = 0; qq < 4; ++qq) {
      const int j = tid + qq * 256;
      const float a0 = aqt[qq * 256];
      const float a1 = aqt[NL + qq * 256];
      const float a2 = aqt[2 * NL + qq * 256];
      const float pen = 1e6f * (1.0f - mask[(size_t)b * NL + j]);
#pragma unroll
      for (int t = 0; t < QT; ++t) {
        const float dx = aqs[0][t] - a0;
        const float dy = aqs[1][t] - a1;
        const float dz = aqs[2][t] - a2;
        s[qq][t] -= spw * sqrtf(dx * dx + dy * dy + dz * dz) + pen;
      }
      *(float4*)&pt[j][0] = make_float4(s[qq][0], s[qq][1], s[qq][2], s[qq][3]);
      *(float4*)&pt[j][4] = make_float4(s[qq][4], s[qq][5], s[qq][6], s[qq][7]);
    }
  }
  __syncthreads();

  // phase 2: softmax — wave w handles rows w and w+4; exp in place, keep 1/sum
  {
    const int wid = tid >> 6, lane = tid & 63;
    for (int r = wid; r < QT; r += 4) {
      float m = -1e30f;
      for (int j = lane; j < NL; j += 64) m = fmaxf(m, pt[j][r]);
#pragma unroll
      for (int off = 32; off; off >>= 1) m = fmaxf(m, __shfl_xor(m, off));
      float ssum = 0.f;
      for (int j = lane; j < NL; j += 64) {
        const float e = __expf(pt[j][r] - m);
        pt[j][r] = e;
        ssum += e;
      }
#pragma unroll
      for (int off = 32; off; off >>= 1) ssum += __shfl_xor(ssum, off);
      if (lane == 0) rinv[r] = 1.0f / ssum;
    }
  }
  __syncthreads();

  // phase 3: weighted sums — thread = (rgroup of 4 rows, dim); 103 dims
  {
    const int rg  = tid >> 7;           // 0 or 1
    const int dim = tid & 127;
    if (dim < 103) {
      const float* src;
      int stride;
      if (dim < 64)       { src = v   + (size_t)bh * NL * NHD + dim;         stride = NHD; }
      else if (dim < 100) { src = vv  + (size_t)bh * NL * NV3 + (dim - 64);  stride = NV3; }
      else                { src = avp + (size_t)bh * NL * 3   + (dim - 100); stride = 3; }
      const int r0 = rg * 4;
      float a0 = 0.f, a1 = 0.f, a2 = 0.f, a3 = 0.f;
#pragma unroll 4
      for (int j = 0; j < NL; ++j) {
        const float sv = src[(size_t)j * stride];
        const float4 pv = *(const float4*)&pt[j][r0];
        a0 = fmaf(pv.x, sv, a0);
        a1 = fmaf(pv.y, sv, a1);
        a2 = fmaf(pv.z, sv, a2);
        a3 = fmaf(pv.w, sv, a3);
      }
      float accs[4] = {a0, a1, a2, a3};
#pragma unroll
      for (int i = 0; i < 4; ++i) {
        const int r = r0 + i;
        const float val = accs[i] * rinv[r];
        const int row = i0 + r;
        if (dim < 64)       sc[((size_t)b * NL + row) * ND + h * NHD + dim] = val;
        else if (dim < 100) vacc[r][dim - 64] = val;
        else                aacc[r][dim - 100] = val;
      }
    }
  }
  __syncthreads();

  // phase 4: output-side rotation (R^T), affine gets -trans first
  for (int u = tid; u < QT * 39; u += 256) {
    const int r = u / 39, w39 = u % 39;
    const size_t l = (size_t)b * NL + i0 + r;
    const float* R = rots + l * 9;
    if (w39 < NV3) {
      const int n = w39 % 3;
      const int base = w39 - n;
      const float val = vacc[r][base]     * R[0 * 3 + n]
                      + vacc[r][base + 1] * R[1 * 3 + n]
                      + vacc[r][base + 2] * R[2 * 3 + n];
      vec[l * 288 + h * NV3 + w39] = val;
    } else {
      const int n = w39 - NV3;
      const float c0 = aacc[r][0] - trans[l * 3 + 0];
      const float c1 = aacc[r][1] - trans[l * 3 + 1];
      const float c2 = aacc[r][2] - trans[l * 3 + 2];
      const float val = c0 * R[0 * 3 + n] + c1 * R[1 * 3 + n] + c2 * R[2 * 3 + n];
      aff[l * 24 + h * 3 + n] = val;
    }
  }
}

// ---------------------------------------------------------------- k_final
__global__ __launch_bounds__(256) void k_final(
    const float* __restrict__ sc, const float* __restrict__ vec,
    const float* __restrict__ aff,
    const float* __restrict__ w_o, const float* __restrict__ w_vo,
    const float* __restrict__ b_vo, const float* __restrict__ w_ao,
    const float* __restrict__ b_ao, float* __restrict__ out)
{
  __shared__ float scs[TOK][ND];
  __shared__ float vcs[TOK][288];
  __shared__ float afs[TOK][24];
  const int tb  = blockIdx.x * TOK;
  const int tid = threadIdx.x;

  for (int i = tid; i < TOK * ND; i += 256)
    scs[i >> 9][i & (ND - 1)] = sc[(size_t)tb * ND + i];
  for (int i = tid; i < TOK * 288; i += 256)
    vcs[i / 288][i % 288] = vec[(size_t)tb * 288 + i];
  for (int i = tid; i < TOK * 24; i += 256)
    afs[i / 24][i % 24] = aff[(size_t)tb * 24 + i];
  __syncthreads();

  for (int n = tid; n < ND; n += 256) {
    float a[TOK];
    const float bias = b_vo[n] + b_ao[n];
#pragma unroll
    for (int t = 0; t < TOK; ++t) a[t] = bias;
    for (int d = 0; d < ND; ++d) {
      const float wv = w_o[d * ND + n];
#pragma unroll
      for (int t = 0; t < TOK; ++t) a[t] = fmaf(scs[t][d], wv, a[t]);
    }
    for (int m = 0; m < 288; ++m) {
      const float wv = w_vo[m * ND + n];
#pragma unroll
      for (int t = 0; t < TOK; ++t) a[t] = fmaf(vcs[t][m], wv, a[t]);
    }
    for (int m = 0; m < 24; ++m) {
      const float wv = w_ao[m * ND + n];
#pragma unroll
      for (int t = 0; t < TOK; ++t) a[t] = fmaf(afs[t][m], wv, a[t]);
    }
#pragma unroll
    for (int t = 0; t < TOK; ++t) out[(size_t)(tb + t) * ND + n] = a[t];
  }
}

} // namespace

extern "C" void kernel_launch(void* const* d_in, const int* in_sizes, int n_in,
                              void* d_out, int out_size, void* d_ws, size_t ws_size,
                              hipStream_t stream)
{
  const float* x       = (const float*)d_in[0];
  const float* mask    = (const float*)d_in[1];
  const float* rots    = (const float*)d_in[2];
  const float* trans   = (const float*)d_in[3];
  const float* w_q     = (const float*)d_in[4];
  const float* w_k     = (const float*)d_in[5];
  const float* w_v     = (const float*)d_in[6];
  const float* w_o     = (const float*)d_in[7];
  const float* w_vq_w  = (const float*)d_in[8];
  const float* w_vq_b  = (const float*)d_in[9];
  const float* w_vk_w  = (const float*)d_in[10];
  const float* w_vk_b  = (const float*)d_in[11];
  const float* w_vv_w  = (const float*)d_in[12];
  const float* w_vv_b  = (const float*)d_in[13];
  const float* w_vo_w  = (const float*)d_in[14];
  const float* w_vo_b  = (const float*)d_in[15];
  const float* w_aq_w  = (const float*)d_in[16];
  const float* w_aq_b  = (const float*)d_in[17];
  const float* w_av_w  = (const float*)d_in[18];
  const float* w_av_b  = (const float*)d_in[19];
  const float* w_ao_w  = (const float*)d_in[20];
  const float* w_ao_b  = (const float*)d_in[21];
  const float* aff_w   = (const float*)d_in[22];
  float* out = (float*)d_out;

  float* ws = (float*)d_ws;
  constexpr size_t SZ_Q   = (size_t)2 * 8 * 1024 * 64;  // 1048576
  constexpr size_t SZ_V36 = (size_t)2 * 8 * 1024 * 36;  // 589824
  constexpr size_t SZ_A3  = (size_t)2 * 8 * 1024 * 3;   // 49152
  float* q    = ws;
  float* k_t  = q   + SZ_Q;
  float* v    = k_t + SZ_Q;
  float* vq   = v   + SZ_Q;
  float* vk_t = vq  + SZ_V36;
  float* vv   = vk_t + SZ_V36;
  float* aq_t = vv  + SZ_V36;
  float* avp  = aq_t + SZ_A3;
  float* sc   = avp + SZ_A3;                      // (B,L,512)
  float* vec  = sc  + (size_t)2 * 1024 * 512;     // (B,L,288)
  float* aff  = vec + (size_t)2 * 1024 * 288;     // (B,L,24)

  k_qkv<<<2048 / TOK, 256, 0, stream>>>(x, w_q, w_k, w_v, q, k_t, v);
  k_proj<<<2048 / TOK, 256, 0, stream>>>(x, rots, trans,
                                         w_vq_w, w_vq_b, w_vk_w, w_vk_b,
                                         w_vv_w, w_vv_b, w_aq_w, w_aq_b,
                                         w_av_w, w_av_b, vq, vk_t, vv, aq_t, avp);
  k_attn<<<2 * 8 * (1024 / QT), 256, 0, stream>>>(q, k_t, v, vq, vk_t, vv,
                                                  aq_t, avp, mask, trans, rots,
                                                  aff_w, sc, vec, aff);
  k_final<<<2048 / TOK, 256, 0, stream>>>(sc, vec, aff, w_o, w_vo_w, w_vo_b,
                                          w_ao_w, w_ao_b, out);
}

// Round 3
// 480.042 us; speedup vs baseline: 2.7787x; 1.8482x over previous
//
#include <hip/hip_runtime.h>
#include <math.h>

namespace {

constexpr int NL  = 1024;  // sequence length
constexpr int ND  = 512;   // model dim
constexpr int NH  = 8;     // heads
constexpr int NHD = 64;    // head dim
constexpr int NV3 = 36;    // 3*VD
constexpr int TOK = 8;     // tokens per block (k_proj)
constexpr int QT  = 8;     // query rows per block (attention)
constexpr int KCAT = 824;  // 512 + 288 + 24

constexpr float SCL_S = 0.044194173824159216f; // 1/sqrt(512)
constexpr float SCL_V = 1.0f / 6.0f;           // 1/sqrt(36)

// ---------------------------------------------------------------- k_qkv
// Tiled GEMM: x[2048x512] @ w[512x512] (w = wq/wk/wv by blockIdx.z).
// Epilogue: z=0 -> RoPE -> q (B,H,L,64); z=1 -> RoPE -> k_t (B,H,64,L);
// z=2 -> v (B,H,L,64).
__global__ __launch_bounds__(256) void k_qkv(
    const float* __restrict__ x,
    const float* __restrict__ wq, const float* __restrict__ wk,
    const float* __restrict__ wv,
    float* __restrict__ q, float* __restrict__ k_t, float* __restrict__ v)
{
  __shared__ float As[16][68];
  __shared__ float Bs[16][64];
  const int tid = threadIdx.x;
  const int tx = tid & 15, ty = tid >> 4;
  const int bm = blockIdx.x * 64;           // token-tile
  const int h  = blockIdx.y;                // head = col-tile (64 cols)
  const int z  = blockIdx.z;
  const float* __restrict__ w = (z == 0) ? wq : (z == 1) ? wk : wv;

  const int am  = tid >> 2;                 // A-load row in tile
  const int ak4 = (tid & 3) * 4;            // A-load k within tile
  const int bk  = tid >> 4;                 // B-load k within tile
  const int bn4 = (tid & 15) * 4;           // B-load col within tile

  float c[4][4];
#pragma unroll
  for (int i = 0; i < 4; ++i)
#pragma unroll
    for (int j = 0; j < 4; ++j) c[i][j] = 0.f;

  float4 aPre = *(const float4*)&x[(size_t)(bm + am) * ND + ak4];
  float4 bPre = *(const float4*)&w[(size_t)bk * ND + h * 64 + bn4];

  for (int kt = 0; kt < 32; ++kt) {
    __syncthreads();
    As[ak4 + 0][am] = aPre.x;
    As[ak4 + 1][am] = aPre.y;
    As[ak4 + 2][am] = aPre.z;
    As[ak4 + 3][am] = aPre.w;
    *(float4*)&Bs[bk][bn4] = bPre;
    __syncthreads();
    if (kt + 1 < 32) {
      const int k0 = (kt + 1) * 16;
      aPre = *(const float4*)&x[(size_t)(bm + am) * ND + k0 + ak4];
      bPre = *(const float4*)&w[(size_t)(k0 + bk) * ND + h * 64 + bn4];
    }
#pragma unroll
    for (int kk = 0; kk < 16; ++kk) {
      const float4 a4 = *(const float4*)&As[kk][ty * 4];
      const float4 b4 = *(const float4*)&Bs[kk][tx * 4];
      const float av[4] = {a4.x, a4.y, a4.z, a4.w};
      const float bv[4] = {b4.x, b4.y, b4.z, b4.w};
#pragma unroll
      for (int i = 0; i < 4; ++i)
#pragma unroll
        for (int j = 0; j < 4; ++j) c[i][j] = fmaf(av[i], bv[j], c[i][j]);
    }
  }

  const int b  = bm >> 10;
  const int l0 = (bm & (NL - 1)) + ty * 4;
  const int hd0 = tx * 4;

  if (z == 2) {
#pragma unroll
    for (int i = 0; i < 4; ++i) {
      *(float4*)&v[((size_t)(b * NH + h) * NL + l0 + i) * NHD + hd0] =
          make_float4(c[i][0], c[i][1], c[i][2], c[i][3]);
    }
    return;
  }

  // RoPE: pairs (hd0,hd0+1) and (hd0+2,hd0+3)
  const float inv0 = powf(10000.0f, -(float)(hd0)     / 64.0f);
  const float inv1 = powf(10000.0f, -(float)(hd0 + 2) / 64.0f);
  float r[4][4];
#pragma unroll
  for (int i = 0; i < 4; ++i) {
    float s0, c0, s1, c1;
    __sincosf((float)(l0 + i) * inv0, &s0, &c0);
    __sincosf((float)(l0 + i) * inv1, &s1, &c1);
    r[i][0] = c[i][0] * c0 - c[i][1] * s0;
    r[i][1] = c[i][0] * s0 + c[i][1] * c0;
    r[i][2] = c[i][2] * c1 - c[i][3] * s1;
    r[i][3] = c[i][2] * s1 + c[i][3] * c1;
  }

  if (z == 0) {
#pragma unroll
    for (int i = 0; i < 4; ++i) {
      *(float4*)&q[((size_t)(b * NH + h) * NL + l0 + i) * NHD + hd0] =
          make_float4(r[i][0], r[i][1], r[i][2], r[i][3]);
    }
  } else {
    // k_t: (bh, 64, L) — per column j store 4 consecutive l
#pragma unroll
    for (int j = 0; j < 4; ++j) {
      *(float4*)&k_t[((size_t)(b * NH + h) * NHD + hd0 + j) * NL + l0] =
          make_float4(r[0][j], r[1][j], r[2][j], r[3][j]);
    }
  }
}

// ---------------------------------------------------------------- k_proj
// vq/vv = rot(x@w+b) layout (B,H,L,36); vk_t = rot(x@w+b) layout (B,H,36,L)
// aq_t = rot(x@w+b)+trans layout (B,H,3,L); av = same, layout (B,H,L,3)
__global__ __launch_bounds__(256) void k_proj(
    const float* __restrict__ x, const float* __restrict__ rots,
    const float* __restrict__ trans,
    const float* __restrict__ wvq, const float* __restrict__ bvq,
    const float* __restrict__ wvk, const float* __restrict__ bvk,
    const float* __restrict__ wvv, const float* __restrict__ bvv,
    const float* __restrict__ waq, const float* __restrict__ baq,
    const float* __restrict__ wav, const float* __restrict__ bav,
    float* __restrict__ vq, float* __restrict__ vk_t, float* __restrict__ vv,
    float* __restrict__ aq_t, float* __restrict__ av)
{
  __shared__ float xs[TOK][ND];
  __shared__ float rq[TOK][288], rk[TOK][288], rv[TOK][288];
  __shared__ float ra[TOK][24], rb[TOK][24];
  const int tb  = blockIdx.x * TOK;
  const int b   = tb >> 10;
  const int tid = threadIdx.x;

  for (int i = tid; i < TOK * ND; i += 256)
    xs[i >> 9][i & (ND - 1)] = x[(size_t)tb * ND + i];
  __syncthreads();

  for (int n = tid; n < 288; n += 256) {
    float a0[TOK], a1[TOK], a2[TOK];
#pragma unroll
    for (int t = 0; t < TOK; ++t) { a0[t] = bvq[n]; a1[t] = bvk[n]; a2[t] = bvv[n]; }
    for (int d = 0; d < ND; ++d) {
      const float w0 = wvq[d * 288 + n];
      const float w1 = wvk[d * 288 + n];
      const float w2 = wvv[d * 288 + n];
#pragma unroll
      for (int t = 0; t < TOK; ++t) {
        const float xv = xs[t][d];
        a0[t] = fmaf(xv, w0, a0[t]);
        a1[t] = fmaf(xv, w1, a1[t]);
        a2[t] = fmaf(xv, w2, a2[t]);
      }
    }
#pragma unroll
    for (int t = 0; t < TOK; ++t) { rq[t][n] = a0[t]; rk[t][n] = a1[t]; rv[t][n] = a2[t]; }
  }
  if (tid < 24) {
    const int n = tid;
    float a0[TOK], a1[TOK];
#pragma unroll
    for (int t = 0; t < TOK; ++t) { a0[t] = baq[n]; a1[t] = bav[n]; }
    for (int d = 0; d < ND; ++d) {
      const float w0 = waq[d * 24 + n];
      const float w1 = wav[d * 24 + n];
#pragma unroll
      for (int t = 0; t < TOK; ++t) {
        const float xv = xs[t][d];
        a0[t] = fmaf(xv, w0, a0[t]);
        a1[t] = fmaf(xv, w1, a1[t]);
      }
    }
#pragma unroll
    for (int t = 0; t < TOK; ++t) { ra[t][n] = a0[t]; rb[t][n] = a1[t]; }
  }
  __syncthreads();

  for (int u = tid; u < TOK * 288; u += 256) {
    const int t = u / 288, n = u % 288;
    const int l = tb + t;
    const int ll = l & (NL - 1);
    const int c = n % 3;
    const int base = n - c;
    const float r0 = rots[(size_t)l * 9 + c * 3 + 0];
    const float r1 = rots[(size_t)l * 9 + c * 3 + 1];
    const float r2 = rots[(size_t)l * 9 + c * 3 + 2];
    const int h = n / NV3;
    const size_t ob = ((size_t)(b * NH + h) * NL + ll) * NV3 + (n % NV3);
    vq[ob] = r0 * rq[t][base] + r1 * rq[t][base + 1] + r2 * rq[t][base + 2];
    vv[ob] = r0 * rv[t][base] + r1 * rv[t][base + 1] + r2 * rv[t][base + 2];
  }
  for (int u = tid; u < TOK * 288; u += 256) {
    const int t = u & 7, n = u >> 3;
    const int l = tb + t;
    const int ll = l & (NL - 1);
    const int c = n % 3;
    const int base = n - c;
    const float r0 = rots[(size_t)l * 9 + c * 3 + 0];
    const float r1 = rots[(size_t)l * 9 + c * 3 + 1];
    const float r2 = rots[(size_t)l * 9 + c * 3 + 2];
    const int h = n / NV3, m = n % NV3;
    vk_t[((size_t)(b * NH + h) * NV3 + m) * NL + ll] =
        r0 * rk[t][base] + r1 * rk[t][base + 1] + r2 * rk[t][base + 2];
  }
  for (int u = tid; u < TOK * 24; u += 256) {
    const int t = u & 7, n = u >> 3;
    const int l = tb + t;
    const int ll = l & (NL - 1);
    const int c = n % 3, h = n / 3;
    const int base = h * 3;
    const float r0 = rots[(size_t)l * 9 + c * 3 + 0];
    const float r1 = rots[(size_t)l * 9 + c * 3 + 1];
    const float r2 = rots[(size_t)l * 9 + c * 3 + 2];
    const float tr = trans[(size_t)l * 3 + c];
    aq_t[((size_t)(b * NH + h) * 3 + c) * NL + ll] =
        r0 * ra[t][base] + r1 * ra[t][base + 1] + r2 * ra[t][base + 2] + tr;
  }
  for (int u = tid; u < TOK * 24; u += 256) {
    const int t = u / 24, n = u % 24;
    const int l = tb + t;
    const int ll = l & (NL - 1);
    const int c = n % 3, h = n / 3;
    const int base = h * 3;
    const float r0 = rots[(size_t)l * 9 + c * 3 + 0];
    const float r1 = rots[(size_t)l * 9 + c * 3 + 1];
    const float r2 = rots[(size_t)l * 9 + c * 3 + 2];
    const float tr = trans[(size_t)l * 3 + c];
    av[((size_t)(b * NH + h) * NL + ll) * 3 + c] =
        r0 * rb[t][base] + r1 * rb[t][base + 1] + r2 * rb[t][base + 2] + tr;
  }
}

// ---------------------------------------------------------------- k_attn
__global__ __launch_bounds__(256) void k_attn(
    const float* __restrict__ q, const float* __restrict__ k_t,
    const float* __restrict__ v, const float* __restrict__ vq,
    const float* __restrict__ vk_t, const float* __restrict__ vv,
    const float* __restrict__ aq_t, const float* __restrict__ avp,
    const float* __restrict__ mask, const float* __restrict__ trans,
    const float* __restrict__ rots, const float* __restrict__ affine_w,
    float* __restrict__ cat)
{
  __shared__ float pt[NL][QT];    // [j][r]
  __shared__ float qs[NHD][QT];   // [d][r]
  __shared__ float vqs[NV3][QT];
  __shared__ float aqs[3][QT];
  __shared__ float vacc[QT][NV3];
  __shared__ float aacc[QT][3];
  __shared__ float rinv[QT];

  const int blk = blockIdx.x;
  const int bh  = blk >> 7;
  const int i0  = (blk & 127) * QT;
  const int b   = bh >> 3, h = bh & 7;
  const int tid = threadIdx.x;

  for (int u = tid; u < NHD * QT; u += 256) {
    const int d = u >> 3, t = u & 7;
    qs[d][t] = q[((size_t)bh * NL + i0 + t) * NHD + d] * SCL_S;
  }
  for (int u = tid; u < NV3 * QT; u += 256) {
    const int d = u >> 3, t = u & 7;
    vqs[d][t] = vq[((size_t)bh * NL + i0 + t) * NV3 + d] * SCL_V;
  }
  if (tid < 3 * QT) {
    const int d = tid >> 3, t = tid & 7;
    aqs[d][t] = aq_t[((size_t)bh * 3 + d) * NL + i0 + t];
  }
  __syncthreads();

  const float spw = logf(1.0f + expf(affine_w[h]));

  // phase 1: logits
  {
    float s[4][QT];
#pragma unroll
    for (int qq = 0; qq < 4; ++qq)
#pragma unroll
      for (int t = 0; t < QT; ++t) s[qq][t] = 0.f;

    const float* kt = k_t + (size_t)bh * NHD * NL + tid;
    for (int d = 0; d < NHD; ++d) {
      const float4 qa = *(const float4*)&qs[d][0];
      const float4 qb = *(const float4*)&qs[d][4];
#pragma unroll
      for (int qq = 0; qq < 4; ++qq) {
        const float kv = kt[(size_t)d * NL + qq * 256];
        s[qq][0] = fmaf(qa.x, kv, s[qq][0]);
        s[qq][1] = fmaf(qa.y, kv, s[qq][1]);
        s[qq][2] = fmaf(qa.z, kv, s[qq][2]);
        s[qq][3] = fmaf(qa.w, kv, s[qq][3]);
        s[qq][4] = fmaf(qb.x, kv, s[qq][4]);
        s[qq][5] = fmaf(qb.y, kv, s[qq][5]);
        s[qq][6] = fmaf(qb.z, kv, s[qq][6]);
        s[qq][7] = fmaf(qb.w, kv, s[qq][7]);
      }
    }
    const float* vkt = vk_t + (size_t)bh * NV3 * NL + tid;
    for (int d = 0; d < NV3; ++d) {
      const float4 qa = *(const float4*)&vqs[d][0];
      const float4 qb = *(const float4*)&vqs[d][4];
#pragma unroll
      for (int qq = 0; qq < 4; ++qq) {
        const float kv = vkt[(size_t)d * NL + qq * 256];
        s[qq][0] = fmaf(qa.x, kv, s[qq][0]);
        s[qq][1] = fmaf(qa.y, kv, s[qq][1]);
        s[qq][2] = fmaf(qa.z, kv, s[qq][2]);
        s[qq][3] = fmaf(qa.w, kv, s[qq][3]);
        s[qq][4] = fmaf(qb.x, kv, s[qq][4]);
        s[qq][5] = fmaf(qb.y, kv, s[qq][5]);
        s[qq][6] = fmaf(qb.z, kv, s[qq][6]);
        s[qq][7] = fmaf(qb.w, kv, s[qq][7]);
      }
    }
    const float* aqt = aq_t + (size_t)bh * 3 * NL + tid;
#pragma unroll
    for (int qq = 0; qq < 4; ++qq) {
      const int j = tid + qq * 256;
      const float a0 = aqt[qq * 256];
      const float a1 = aqt[NL + qq * 256];
      const float a2 = aqt[2 * NL + qq * 256];
      const float pen = 1e6f * (1.0f - mask[(size_t)b * NL + j]);
#pragma unroll
      for (int t = 0; t < QT; ++t) {
        const float dx = aqs[0][t] - a0;
        const float dy = aqs[1][t] - a1;
        const float dz = aqs[2][t] - a2;
        s[qq][t] -= spw * sqrtf(dx * dx + dy * dy + dz * dz) + pen;
      }
      *(float4*)&pt[j][0] = make_float4(s[qq][0], s[qq][1], s[qq][2], s[qq][3]);
      *(float4*)&pt[j][4] = make_float4(s[qq][4], s[qq][5], s[qq][6], s[qq][7]);
    }
  }
  __syncthreads();

  // phase 2: softmax
  {
    const int wid = tid >> 6, lane = tid & 63;
    for (int r = wid; r < QT; r += 4) {
      float m = -1e30f;
      for (int j = lane; j < NL; j += 64) m = fmaxf(m, pt[j][r]);
#pragma unroll
      for (int off = 32; off; off >>= 1) m = fmaxf(m, __shfl_xor(m, off));
      float ssum = 0.f;
      for (int j = lane; j < NL; j += 64) {
        const float e = __expf(pt[j][r] - m);
        pt[j][r] = e;
        ssum += e;
      }
#pragma unroll
      for (int off = 32; off; off >>= 1) ssum += __shfl_xor(ssum, off);
      if (lane == 0) rinv[r] = 1.0f / ssum;
    }
  }
  __syncthreads();

  // phase 3: weighted sums -> cat[., 0:512) for scalar; vacc/aacc for rest
  {
    const int rg  = tid >> 7;
    const int dim = tid & 127;
    if (dim < 103) {
      const float* src;
      int stride;
      if (dim < 64)       { src = v   + (size_t)bh * NL * NHD + dim;         stride = NHD; }
      else if (dim < 100) { src = vv  + (size_t)bh * NL * NV3 + (dim - 64);  stride = NV3; }
      else                { src = avp + (size_t)bh * NL * 3   + (dim - 100); stride = 3; }
      const int r0 = rg * 4;
      float a0 = 0.f, a1 = 0.f, a2 = 0.f, a3 = 0.f;
#pragma unroll 4
      for (int j = 0; j < NL; ++j) {
        const float sv = src[(size_t)j * stride];
        const float4 pv = *(const float4*)&pt[j][r0];
        a0 = fmaf(pv.x, sv, a0);
        a1 = fmaf(pv.y, sv, a1);
        a2 = fmaf(pv.z, sv, a2);
        a3 = fmaf(pv.w, sv, a3);
      }
      float accs[4] = {a0, a1, a2, a3};
#pragma unroll
      for (int i = 0; i < 4; ++i) {
        const int r = r0 + i;
        const float val = accs[i] * rinv[r];
        const int row = i0 + r;
        if (dim < 64)       cat[((size_t)b * NL + row) * KCAT + h * NHD + dim] = val;
        else if (dim < 100) vacc[r][dim - 64] = val;
        else                aacc[r][dim - 100] = val;
      }
    }
  }
  __syncthreads();

  // phase 4: output-side rotation (R^T) -> cat[., 512:800) and cat[., 800:824)
  for (int u = tid; u < QT * 39; u += 256) {
    const int r = u / 39, w39 = u % 39;
    const size_t l = (size_t)b * NL + i0 + r;
    const float* R = rots + l * 9;
    if (w39 < NV3) {
      const int n = w39 % 3;
      const int base = w39 - n;
      const float val = vacc[r][base]     * R[0 * 3 + n]
                      + vacc[r][base + 1] * R[1 * 3 + n]
                      + vacc[r][base + 2] * R[2 * 3 + n];
      cat[l * KCAT + 512 + h * NV3 + w39] = val;
    } else {
      const int n = w39 - NV3;
      const float c0 = aacc[r][0] - trans[l * 3 + 0];
      const float c1 = aacc[r][1] - trans[l * 3 + 1];
      const float c2 = aacc[r][2] - trans[l * 3 + 2];
      const float val = c0 * R[0 * 3 + n] + c1 * R[1 * 3 + n] + c2 * R[2 * 3 + n];
      cat[l * KCAT + 800 + h * 3 + n] = val;
    }
  }
}

// ---------------------------------------------------------------- k_final
// Tiled GEMM: out[2048x512] = cat[2048x824] @ [w_o; w_vo; w_ao] + b_vo + b_ao
__global__ __launch_bounds__(256) void k_final(
    const float* __restrict__ cat,
    const float* __restrict__ w_o, const float* __restrict__ w_vo,
    const float* __restrict__ b_vo, const float* __restrict__ w_ao,
    const float* __restrict__ b_ao, float* __restrict__ out)
{
  __shared__ float As[16][68];
  __shared__ float Bs[16][64];
  const int tid = threadIdx.x;
  const int tx = tid & 15, ty = tid >> 4;
  const int bm = blockIdx.x * 64;
  const int bn = blockIdx.y * 64;

  const int am  = tid >> 2;
  const int ak4 = (tid & 3) * 4;
  const int bk  = tid >> 4;
  const int bn4 = (tid & 15) * 4;

  float c[4][4];
#pragma unroll
  for (int i = 0; i < 4; ++i)
#pragma unroll
    for (int j = 0; j < 4; ++j) c[i][j] = 0.f;

  const float4 zero4 = make_float4(0.f, 0.f, 0.f, 0.f);

  auto loadA = [&](int k0) -> float4 {
    const int k = k0 + ak4;
    return (k + 3 < KCAT) ? *(const float4*)&cat[(size_t)(bm + am) * KCAT + k]
                          : zero4;
  };
  auto loadB = [&](int k0) -> float4 {
    const int k = k0 + bk;
    if (k < 512)      return *(const float4*)&w_o [(size_t)k * ND + bn + bn4];
    else if (k < 800) return *(const float4*)&w_vo[(size_t)(k - 512) * ND + bn + bn4];
    else if (k < 824) return *(const float4*)&w_ao[(size_t)(k - 800) * ND + bn + bn4];
    return zero4;
  };

  float4 aPre = loadA(0);
  float4 bPre = loadB(0);

  constexpr int NT = 52;  // ceil(824/16)
  for (int kt = 0; kt < NT; ++kt) {
    __syncthreads();
    As[ak4 + 0][am] = aPre.x;
    As[ak4 + 1][am] = aPre.y;
    As[ak4 + 2][am] = aPre.z;
    As[ak4 + 3][am] = aPre.w;
    *(float4*)&Bs[bk][bn4] = bPre;
    __syncthreads();
    if (kt + 1 < NT) {
      aPre = loadA((kt + 1) * 16);
      bPre = loadB((kt + 1) * 16);
    }
#pragma unroll
    for (int kk = 0; kk < 16; ++kk) {
      const float4 a4 = *(const float4*)&As[kk][ty * 4];
      const float4 b4 = *(const float4*)&Bs[kk][tx * 4];
      const float av[4] = {a4.x, a4.y, a4.z, a4.w};
      const float bv[4] = {b4.x, b4.y, b4.z, b4.w};
#pragma unroll
      for (int i = 0; i < 4; ++i)
#pragma unroll
        for (int j = 0; j < 4; ++j) c[i][j] = fmaf(av[i], bv[j], c[i][j]);
    }
  }

  const int n0 = bn + tx * 4;
  const float4 bias = make_float4(b_vo[n0] + b_ao[n0],
                                  b_vo[n0 + 1] + b_ao[n0 + 1],
                                  b_vo[n0 + 2] + b_ao[n0 + 2],
                                  b_vo[n0 + 3] + b_ao[n0 + 3]);
#pragma unroll
  for (int i = 0; i < 4; ++i) {
    const int m = bm + ty * 4 + i;
    *(float4*)&out[(size_t)m * ND + n0] =
        make_float4(c[i][0] + bias.x, c[i][1] + bias.y,
                    c[i][2] + bias.z, c[i][3] + bias.w);
  }
}

} // namespace

extern "C" void kernel_launch(void* const* d_in, const int* in_sizes, int n_in,
                              void* d_out, int out_size, void* d_ws, size_t ws_size,
                              hipStream_t stream)
{
  const float* x       = (const float*)d_in[0];
  const float* mask    = (const float*)d_in[1];
  const float* rots    = (const float*)d_in[2];
  const float* trans   = (const float*)d_in[3];
  const float* w_q     = (const float*)d_in[4];
  const float* w_k     = (const float*)d_in[5];
  const float* w_v     = (const float*)d_in[6];
  const float* w_o     = (const float*)d_in[7];
  const float* w_vq_w  = (const float*)d_in[8];
  const float* w_vq_b  = (const float*)d_in[9];
  const float* w_vk_w  = (const float*)d_in[10];
  const float* w_vk_b  = (const float*)d_in[11];
  const float* w_vv_w  = (const float*)d_in[12];
  const float* w_vv_b  = (const float*)d_in[13];
  const float* w_vo_w  = (const float*)d_in[14];
  const float* w_vo_b  = (const float*)d_in[15];
  const float* w_aq_w  = (const float*)d_in[16];
  const float* w_aq_b  = (const float*)d_in[17];
  const float* w_av_w  = (const float*)d_in[18];
  const float* w_av_b  = (const float*)d_in[19];
  const float* w_ao_w  = (const float*)d_in[20];
  const float* w_ao_b  = (const float*)d_in[21];
  const float* aff_w   = (const float*)d_in[22];
  float* out = (float*)d_out;

  float* ws = (float*)d_ws;
  constexpr size_t SZ_Q   = (size_t)2 * 8 * 1024 * 64;
  constexpr size_t SZ_V36 = (size_t)2 * 8 * 1024 * 36;
  constexpr size_t SZ_A3  = (size_t)2 * 8 * 1024 * 3;
  float* q    = ws;
  float* k_t  = q    + SZ_Q;
  float* v    = k_t  + SZ_Q;
  float* vq   = v    + SZ_Q;
  float* vk_t = vq   + SZ_V36;
  float* vv   = vk_t + SZ_V36;
  float* aq_t = vv   + SZ_V36;
  float* avp  = aq_t + SZ_A3;
  float* cat  = avp  + SZ_A3;   // (B*L, 824)

  k_qkv<<<dim3(32, 8, 3), 256, 0, stream>>>(x, w_q, w_k, w_v, q, k_t, v);
  k_proj<<<2048 / TOK, 256, 0, stream>>>(x, rots, trans,
                                         w_vq_w, w_vq_b, w_vk_w, w_vk_b,
                                         w_vv_w, w_vv_b, w_aq_w, w_aq_b,
                                         w_av_w, w_av_b, vq, vk_t, vv, aq_t, avp);
  k_attn<<<2 * 8 * (1024 / QT), 256, 0, stream>>>(q, k_t, v, vq, vk_t, vv,
                                                  aq_t, avp, mask, trans, rots,
                                                  aff_w, cat);
  k_final<<<dim3(32, 8), 256, 0, stream>>>(cat, w_o, w_vo_w, w_vo_b,
                                           w_ao_w, w_ao_b, out);
}

// Round 5
// 258.951 us; speedup vs baseline: 5.1512x; 1.8538x over previous
//
#include <hip/hip_runtime.h>
#include <math.h>

namespace {

typedef __attribute__((ext_vector_type(8))) short short8;
typedef __attribute__((ext_vector_type(4))) float f32x4;

constexpr int NL  = 1024;
constexpr int ND  = 512;
constexpr int NH  = 8;
constexpr int NHD = 64;
constexpr int NV3 = 36;
constexpr int QT  = 8;
constexpr int NCAT = 2560;   // packed projection output cols (2448 used)
constexpr int KF   = 832;    // final-GEMM K (824 used)

constexpr float SCL_S = 0.044194173824159216f; // 1/sqrt(512)
constexpr float SCL_V = 1.0f / 6.0f;           // 1/sqrt(36)

__device__ inline ushort f2bf(float f) {
  uint u = __float_as_uint(f);
  u += 0x7FFFu + ((u >> 16) & 1u);
  return (ushort)(u >> 16);
}
__device__ inline float bf2f(ushort h) { return __uint_as_float((uint)h << 16); }

// ---------------------------------------------------------------- k_pack
// z=0: wcat hi/lo [2560][512] bf16 = [wq|wk|wv|wvq|wvk|wvv|waq|wav]^T
// z=1: wcat2 [512][832] bf16 = [w_o;w_vo;w_ao]^T with K-pad zeros
__global__ __launch_bounds__(256) void k_pack(
    const float* __restrict__ wq, const float* __restrict__ wk,
    const float* __restrict__ wv, const float* __restrict__ wvq,
    const float* __restrict__ wvk, const float* __restrict__ wvv,
    const float* __restrict__ waq, const float* __restrict__ wav,
    const float* __restrict__ w_o, const float* __restrict__ w_vo,
    const float* __restrict__ w_ao,
    ushort* __restrict__ wch, ushort* __restrict__ wcl,
    ushort* __restrict__ wcat2)
{
  __shared__ float t[64][65];
  const int tid = threadIdx.x;
  const int z = blockIdx.z;
  if (z == 0) { if (blockIdx.y >= 8) return; }
  else        { if (blockIdx.x >= 8) return; }
  const int n0 = blockIdx.x * 64, k0 = blockIdx.y * 64;
  const int rr = tid >> 6, cc = tid & 63;

  for (int p = 0; p < 16; ++p) {
    const int kk = k0 + p * 4 + rr;
    const int nn = n0 + cc;
    float val;
    if (z == 0) {
      if (nn < 1536) {
        const float* w = nn < 512 ? wq : (nn < 1024 ? wk : wv);
        val = w[(size_t)kk * 512 + (nn & 511)];
      } else if (nn < 2400) {
        const float* w = nn < 1824 ? wvq : (nn < 2112 ? wvk : wvv);
        val = w[(size_t)kk * 288 + (nn - 1536) % 288];
      } else if (nn < 2424) val = waq[(size_t)kk * 24 + nn - 2400];
      else if (nn < 2448)   val = wav[(size_t)kk * 24 + nn - 2424];
      else val = 0.f;
    } else {
      if (kk < 512)      val = w_o [(size_t)kk * 512 + nn];
      else if (kk < 800) val = w_vo[(size_t)(kk - 512) * 512 + nn];
      else if (kk < 824) val = w_ao[(size_t)(kk - 800) * 512 + nn];
      else val = 0.f;
    }
    t[p * 4 + rr][cc] = val;
  }
  __syncthreads();
  for (int p = 0; p < 16; ++p) {
    const int nn = p * 4 + rr;
    const int kk = cc;
    const float val = t[kk][nn];
    const ushort h16 = f2bf(val);
    if (z == 0) {
      wch[(size_t)(n0 + nn) * 512 + k0 + kk] = h16;
      wcl[(size_t)(n0 + nn) * 512 + k0 + kk] = f2bf(val - bf2f(h16));
    } else {
      wcat2[(size_t)(n0 + nn) * 832 + k0 + kk] = h16;
    }
  }
}

// ---------------------------------------------------------------- k_cvtx
__global__ __launch_bounds__(256) void k_cvtx(const float* __restrict__ x,
                                              ushort* __restrict__ xh,
                                              ushort* __restrict__ xl)
{
  const int i = (blockIdx.x * 256 + threadIdx.x) * 4;
  const float4 v = *(const float4*)&x[i];
  ushort4 h, l;
  h.x = f2bf(v.x); l.x = f2bf(v.x - bf2f(h.x));
  h.y = f2bf(v.y); l.y = f2bf(v.y - bf2f(h.y));
  h.z = f2bf(v.z); l.z = f2bf(v.z - bf2f(h.z));
  h.w = f2bf(v.w); l.w = f2bf(v.w - bf2f(h.w));
  *(ushort4*)&xh[i] = h;
  *(ushort4*)&xl[i] = l;
}

// ---------------------------------------------------------------- k_mm
// Y[M][N] (fp32) = (Ah+Al)[M][K] @ (Bh+Bl)[N][K]^T, split-bf16 3-term MFMA.
__global__ __launch_bounds__(256) void k_mm(
    const ushort* __restrict__ Ah, const ushort* __restrict__ Al,
    const ushort* __restrict__ Bh, const ushort* __restrict__ Bl,
    float* __restrict__ Y, int N, int K)
{
  __shared__ __align__(16) ushort Ahs[128][40];
  __shared__ __align__(16) ushort Als[128][40];
  __shared__ __align__(16) ushort Bhs[128][40];
  __shared__ __align__(16) ushort Bls[128][40];
  const int tid = threadIdx.x;
  const int m0 = blockIdx.x * 128, n0 = blockIdx.y * 128;
  const int w = tid >> 6, lane = tid & 63;
  const int wm = (w & 1) * 64, wn = (w >> 1) * 64;
  const int fr = lane & 15, fg = lane >> 4;

  f32x4 acc[4][4];
#pragma unroll
  for (int i = 0; i < 4; ++i)
#pragma unroll
    for (int j = 0; j < 4; ++j) acc[i][j] = (f32x4){0.f, 0.f, 0.f, 0.f};

  const int sr = tid >> 1, sk = (tid & 1) * 16;
  const ushort* agh = Ah + (size_t)(m0 + sr) * K + sk;
  const ushort* agl = Al + (size_t)(m0 + sr) * K + sk;
  const ushort* bgh = Bh + (size_t)(n0 + sr) * K + sk;
  const ushort* bgl = Bl + (size_t)(n0 + sr) * K + sk;
  short8 pah0 = *(const short8*)agh, pah1 = *(const short8*)(agh + 8);
  short8 pal0 = *(const short8*)agl, pal1 = *(const short8*)(agl + 8);
  short8 pbh0 = *(const short8*)bgh, pbh1 = *(const short8*)(bgh + 8);
  short8 pbl0 = *(const short8*)bgl, pbl1 = *(const short8*)(bgl + 8);

  const int NT = K >> 5;
  for (int kt = 0; kt < NT; ++kt) {
    __syncthreads();
    *(short8*)&Ahs[sr][sk] = pah0; *(short8*)&Ahs[sr][sk + 8] = pah1;
    *(short8*)&Als[sr][sk] = pal0; *(short8*)&Als[sr][sk + 8] = pal1;
    *(short8*)&Bhs[sr][sk] = pbh0; *(short8*)&Bhs[sr][sk + 8] = pbh1;
    *(short8*)&Bls[sr][sk] = pbl0; *(short8*)&Bls[sr][sk + 8] = pbl1;
    __syncthreads();
    if (kt + 1 < NT) {
      const size_t off = (size_t)(kt + 1) * 32;
      pah0 = *(const short8*)(agh + off); pah1 = *(const short8*)(agh + off + 8);
      pal0 = *(const short8*)(agl + off); pal1 = *(const short8*)(agl + off + 8);
      pbh0 = *(const short8*)(bgh + off); pbh1 = *(const short8*)(bgh + off + 8);
      pbl0 = *(const short8*)(bgl + off); pbl1 = *(const short8*)(bgl + off + 8);
    }
    short8 fah[4], fal[4], fbh[4], fbl[4];
#pragma unroll
    for (int i = 0; i < 4; ++i) {
      fah[i] = *(const short8*)&Ahs[wm + i * 16 + fr][fg * 8];
      fal[i] = *(const short8*)&Als[wm + i * 16 + fr][fg * 8];
    }
#pragma unroll
    for (int j = 0; j < 4; ++j) {
      fbh[j] = *(const short8*)&Bhs[wn + j * 16 + fr][fg * 8];
      fbl[j] = *(const short8*)&Bls[wn + j * 16 + fr][fg * 8];
    }
#pragma unroll
    for (int i = 0; i < 4; ++i)
#pragma unroll
      for (int j = 0; j < 4; ++j) {
        f32x4 t = __builtin_amdgcn_mfma_f32_16x16x32_bf16(fah[i], fbh[j], acc[i][j], 0, 0, 0);
        t = __builtin_amdgcn_mfma_f32_16x16x32_bf16(fal[i], fbh[j], t, 0, 0, 0);
        t = __builtin_amdgcn_mfma_f32_16x16x32_bf16(fah[i], fbl[j], t, 0, 0, 0);
        acc[i][j] = t;
      }
  }

  const int rb = fg * 4;
#pragma unroll
  for (int i = 0; i < 4; ++i)
#pragma unroll
    for (int j = 0; j < 4; ++j) {
      const int n = n0 + wn + j * 16 + fr;
#pragma unroll
      for (int r = 0; r < 4; ++r) {
        const int m = m0 + wm + i * 16 + rb + r;
        Y[(size_t)m * N + n] = acc[i][j][r];
      }
    }
}

// ---------------------------------------------------------------- k_fin
// out[M][512] (fp32) = cat[M][832] @ wcat2[512][832]^T + b_vo + b_ao
__global__ __launch_bounds__(256) void k_fin(
    const ushort* __restrict__ A, const ushort* __restrict__ Bt,
    const float* __restrict__ b_vo, const float* __restrict__ b_ao,
    float* __restrict__ out)
{
  __shared__ __align__(16) ushort As[128][40];
  __shared__ __align__(16) ushort Bs[128][40];
  const int tid = threadIdx.x;
  const int m0 = blockIdx.x * 128, n0 = blockIdx.y * 128;
  const int w = tid >> 6, lane = tid & 63;
  const int wm = (w & 1) * 64, wn = (w >> 1) * 64;
  const int fr = lane & 15, fg = lane >> 4;
  const int K = KF;

  f32x4 acc[4][4];
#pragma unroll
  for (int i = 0; i < 4; ++i)
#pragma unroll
    for (int j = 0; j < 4; ++j) acc[i][j] = (f32x4){0.f, 0.f, 0.f, 0.f};

  const int sr = tid >> 1, sk = (tid & 1) * 16;
  const ushort* ag = A + (size_t)(m0 + sr) * K + sk;
  const ushort* bg = Bt + (size_t)(n0 + sr) * K + sk;
  short8 a0 = *(const short8*)ag;
  short8 a1 = *(const short8*)(ag + 8);
  short8 b0 = *(const short8*)bg;
  short8 b1 = *(const short8*)(bg + 8);

  const int NT = K >> 5;  // 26
  for (int kt = 0; kt < NT; ++kt) {
    __syncthreads();
    *(short8*)&As[sr][sk] = a0; *(short8*)&As[sr][sk + 8] = a1;
    *(short8*)&Bs[sr][sk] = b0; *(short8*)&Bs[sr][sk + 8] = b1;
    __syncthreads();
    if (kt + 1 < NT) {
      const ushort* agn = ag + (size_t)(kt + 1) * 32;
      const ushort* bgn = bg + (size_t)(kt + 1) * 32;
      a0 = *(const short8*)agn; a1 = *(const short8*)(agn + 8);
      b0 = *(const short8*)bgn; b1 = *(const short8*)(bgn + 8);
    }
    short8 aF[4], bF[4];
#pragma unroll
    for (int i = 0; i < 4; ++i) aF[i] = *(const short8*)&As[wm + i * 16 + fr][fg * 8];
#pragma unroll
    for (int j = 0; j < 4; ++j) bF[j] = *(const short8*)&Bs[wn + j * 16 + fr][fg * 8];
#pragma unroll
    for (int i = 0; i < 4; ++i)
#pragma unroll
      for (int j = 0; j < 4; ++j)
        acc[i][j] = __builtin_amdgcn_mfma_f32_16x16x32_bf16(aF[i], bF[j], acc[i][j], 0, 0, 0);
  }

  const int rb = fg * 4;
#pragma unroll
  for (int j = 0; j < 4; ++j) {
    const int n = n0 + wn + j * 16 + fr;
    const float bias = b_vo[n] + b_ao[n];
#pragma unroll
    for (int i = 0; i < 4; ++i)
#pragma unroll
      for (int r = 0; r < 4; ++r) {
        const int m = m0 + wm + i * 16 + rb + r;
        out[(size_t)m * ND + n] = acc[i][j][r] + bias;
      }
  }
}

// ---------------------------------------------------------------- k_rope
// From fp32 Y: q (bh,L,64), k_t (bh,64,L), v (bh,L,64).
__global__ __launch_bounds__(256) void k_rope(
    const float* __restrict__ Y,
    float* __restrict__ q, float* __restrict__ k_t, float* __restrict__ v)
{
  __shared__ float t0[64][65];
  __shared__ float t1[64][73];
  const int tid = threadIdx.x;
  const int l0 = blockIdx.x * 64, h = blockIdx.y;
  const int b = l0 >> 10, ll0 = l0 & 1023;
  const int rr = tid >> 6, cc = tid & 63;
  const float inv = powf(10000.f, -(float)(cc & ~1) / 64.f);
  const bool odd = (cc & 1) != 0;

  // ---- q ----
  for (int p = 0; p < 16; ++p) {
    const int r = p * 4 + rr;
    t0[r][cc] = Y[(size_t)(l0 + r) * NCAT + h * 64 + cc];
  }
  __syncthreads();
  for (int p = 0; p < 16; ++p) {
    const int r = p * 4 + rr;
    float sv, cv;
    __sincosf((float)(ll0 + r) * inv, &sv, &cv);
    const float e = t0[r][cc & ~1], o = t0[r][(cc & ~1) + 1];
    const float val = odd ? fmaf(e, sv, o * cv) : fmaf(e, cv, -o * sv);
    q[((size_t)(b * NH + h) * NL + ll0 + r) * NHD + cc] = val;
  }
  __syncthreads();
  // ---- k ----
  for (int p = 0; p < 16; ++p) {
    const int r = p * 4 + rr;
    t0[r][cc] = Y[(size_t)(l0 + r) * NCAT + 512 + h * 64 + cc];
  }
  __syncthreads();
  for (int p = 0; p < 16; ++p) {
    const int r = p * 4 + rr;
    float sv, cv;
    __sincosf((float)(ll0 + r) * inv, &sv, &cv);
    const float e = t0[r][cc & ~1], o = t0[r][(cc & ~1) + 1];
    t1[cc][r] = odd ? fmaf(e, sv, o * cv) : fmaf(e, cv, -o * sv);
  }
  __syncthreads();
  for (int p = 0; p < 16; ++p) {
    const int hd = p * 4 + rr;
    k_t[((size_t)(b * NH + h) * NHD + hd) * NL + ll0 + cc] = t1[hd][cc];
  }
  // ---- v ----
  for (int p = 0; p < 16; ++p) {
    const int r = p * 4 + rr;
    v[((size_t)(b * NH + h) * NL + ll0 + r) * NHD + cc] =
        Y[(size_t)(l0 + r) * NCAT + 1024 + h * 64 + cc];
  }
}

// ---------------------------------------------------------------- k_rot
__global__ __launch_bounds__(256) void k_rot(
    const float* __restrict__ Y,
    const float* __restrict__ rots, const float* __restrict__ trans,
    const float* __restrict__ bvq, const float* __restrict__ bvk,
    const float* __restrict__ bvv, const float* __restrict__ baq,
    const float* __restrict__ bav,
    float* __restrict__ vq, float* __restrict__ vk_t, float* __restrict__ vv,
    float* __restrict__ aq_t, float* __restrict__ av)
{
  __shared__ float ys[8][912];
  const int tb = blockIdx.x * 8;
  const int b = tb >> 10;
  const int tid = threadIdx.x;

  for (int t = 0; t < 8; ++t)
    for (int n = tid; n < 912; n += 256)
      ys[t][n] = Y[(size_t)(tb + t) * NCAT + 1536 + n];
  __syncthreads();

  // vq, vv  (bh, L, 36)
  for (int u = tid; u < 8 * 288; u += 256) {
    const int t = u / 288, n = u % 288;
    const int l = tb + t, ll = l & 1023;
    const int c = n % 3, base = n - c;
    const float r0 = rots[(size_t)l * 9 + c * 3 + 0];
    const float r1 = rots[(size_t)l * 9 + c * 3 + 1];
    const float r2 = rots[(size_t)l * 9 + c * 3 + 2];
    const int h = n / NV3;
    const size_t ob = ((size_t)(b * NH + h) * NL + ll) * NV3 + (n % NV3);
    vq[ob] = r0 * (ys[t][base] + bvq[base]) + r1 * (ys[t][base + 1] + bvq[base + 1])
           + r2 * (ys[t][base + 2] + bvq[base + 2]);
    vv[ob] = r0 * (ys[t][576 + base] + bvv[base]) + r1 * (ys[t][577 + base] + bvv[base + 1])
           + r2 * (ys[t][578 + base] + bvv[base + 2]);
  }
  // vk_t (bh, 36, L)
  for (int u = tid; u < 8 * 288; u += 256) {
    const int t = u & 7, n = u >> 3;
    const int l = tb + t, ll = l & 1023;
    const int c = n % 3, base = n - c;
    const float r0 = rots[(size_t)l * 9 + c * 3 + 0];
    const float r1 = rots[(size_t)l * 9 + c * 3 + 1];
    const float r2 = rots[(size_t)l * 9 + c * 3 + 2];
    const int h = n / NV3, m = n % NV3;
    vk_t[((size_t)(b * NH + h) * NV3 + m) * NL + ll] =
        r0 * (ys[t][288 + base] + bvk[base]) + r1 * (ys[t][289 + base] + bvk[base + 1])
      + r2 * (ys[t][290 + base] + bvk[base + 2]);
  }
  // aq_t (bh, 3, L)
  for (int u = tid; u < 8 * 24; u += 256) {
    const int t = u & 7, n = u >> 3;
    const int l = tb + t, ll = l & 1023;
    const int c = n % 3, h = n / 3, base = h * 3;
    const float r0 = rots[(size_t)l * 9 + c * 3 + 0];
    const float r1 = rots[(size_t)l * 9 + c * 3 + 1];
    const float r2 = rots[(size_t)l * 9 + c * 3 + 2];
    const float tr = trans[(size_t)l * 3 + c];
    aq_t[((size_t)(b * NH + h) * 3 + c) * NL + ll] =
        r0 * (ys[t][864 + base] + baq[base]) + r1 * (ys[t][865 + base] + baq[base + 1])
      + r2 * (ys[t][866 + base] + baq[base + 2]) + tr;
  }
  // av (bh, L, 3)
  for (int u = tid; u < 8 * 24; u += 256) {
    const int t = u / 24, n = u % 24;
    const int l = tb + t, ll = l & 1023;
    const int c = n % 3, h = n / 3, base = h * 3;
    const float r0 = rots[(size_t)l * 9 + c * 3 + 0];
    const float r1 = rots[(size_t)l * 9 + c * 3 + 1];
    const float r2 = rots[(size_t)l * 9 + c * 3 + 2];
    const float tr = trans[(size_t)l * 3 + c];
    av[((size_t)(b * NH + h) * NL + ll) * 3 + c] =
        r0 * (ys[t][888 + base] + bav[base]) + r1 * (ys[t][889 + base] + bav[base + 1])
      + r2 * (ys[t][890 + base] + bav[base + 2]) + tr;
  }
}

// ---------------------------------------------------------------- k_attn
__global__ __launch_bounds__(256) void k_attn(
    const float* __restrict__ q, const float* __restrict__ k_t,
    const float* __restrict__ v, const float* __restrict__ vq,
    const float* __restrict__ vk_t, const float* __restrict__ vv,
    const float* __restrict__ aq_t, const float* __restrict__ avp,
    const float* __restrict__ mask, const float* __restrict__ trans,
    const float* __restrict__ rots, const float* __restrict__ affine_w,
    ushort* __restrict__ catb)
{
  __shared__ float pt[NL][QT];    // [j][r]
  __shared__ float qs[NHD][QT];
  __shared__ float vqs[NV3][QT];
  __shared__ float aqs[3][QT];
  __shared__ float vacc[QT][NV3];
  __shared__ float aacc[QT][3];
  __shared__ float rinv[QT];
  __shared__ float red_m[2][2][4];
  __shared__ float red_s[2][2][4];

  const int blk = blockIdx.x;
  const int bh  = blk >> 7;
  const int i0  = (blk & 127) * QT;
  const int b   = bh >> 3, h = bh & 7;
  const int tid = threadIdx.x;

  for (int u = tid; u < NHD * QT; u += 256) {
    const int d = u >> 3, t = u & 7;
    qs[d][t] = q[((size_t)bh * NL + i0 + t) * NHD + d] * SCL_S;
  }
  for (int u = tid; u < NV3 * QT; u += 256) {
    const int d = u >> 3, t = u & 7;
    vqs[d][t] = vq[((size_t)bh * NL + i0 + t) * NV3 + d] * SCL_V;
  }
  if (tid < 3 * QT) {
    const int d = tid >> 3, t = tid & 7;
    aqs[d][t] = aq_t[((size_t)bh * 3 + d) * NL + i0 + t];
  }
  __syncthreads();

  const float spw = logf(1.0f + expf(affine_w[h]));

  // phase 1: logits
  {
    float s[4][QT];
#pragma unroll
    for (int qq = 0; qq < 4; ++qq)
#pragma unroll
      for (int t = 0; t < QT; ++t) s[qq][t] = 0.f;

    const float* kt = k_t + (size_t)bh * NHD * NL + tid;
#pragma unroll 2
    for (int d = 0; d < NHD; ++d) {
      const float4 qa = *(const float4*)&qs[d][0];
      const float4 qb = *(const float4*)&qs[d][4];
#pragma unroll
      for (int qq = 0; qq < 4; ++qq) {
        const float kv = kt[(size_t)d * NL + qq * 256];
        s[qq][0] = fmaf(qa.x, kv, s[qq][0]);
        s[qq][1] = fmaf(qa.y, kv, s[qq][1]);
        s[qq][2] = fmaf(qa.z, kv, s[qq][2]);
        s[qq][3] = fmaf(qa.w, kv, s[qq][3]);
        s[qq][4] = fmaf(qb.x, kv, s[qq][4]);
        s[qq][5] = fmaf(qb.y, kv, s[qq][5]);
        s[qq][6] = fmaf(qb.z, kv, s[qq][6]);
        s[qq][7] = fmaf(qb.w, kv, s[qq][7]);
      }
    }
    const float* vkt = vk_t + (size_t)bh * NV3 * NL + tid;
#pragma unroll 2
    for (int d = 0; d < NV3; ++d) {
      const float4 qa = *(const float4*)&vqs[d][0];
      const float4 qb = *(const float4*)&vqs[d][4];
#pragma unroll
      for (int qq = 0; qq < 4; ++qq) {
        const float kv = vkt[(size_t)d * NL + qq * 256];
        s[qq][0] = fmaf(qa.x, kv, s[qq][0]);
        s[qq][1] = fmaf(qa.y, kv, s[qq][1]);
        s[qq][2] = fmaf(qa.z, kv, s[qq][2]);
        s[qq][3] = fmaf(qa.w, kv, s[qq][3]);
        s[qq][4] = fmaf(qb.x, kv, s[qq][4]);
        s[qq][5] = fmaf(qb.y, kv, s[qq][5]);
        s[qq][6] = fmaf(qb.z, kv, s[qq][6]);
        s[qq][7] = fmaf(qb.w, kv, s[qq][7]);
      }
    }
    const float* aqt = aq_t + (size_t)bh * 3 * NL + tid;
#pragma unroll
    for (int qq = 0; qq < 4; ++qq) {
      const int j = tid + qq * 256;
      const float a0 = aqt[qq * 256];
      const float a1 = aqt[NL + qq * 256];
      const float a2 = aqt[2 * NL + qq * 256];
      const float pen = 1e6f * (1.0f - mask[(size_t)b * NL + j]);
#pragma unroll
      for (int t = 0; t < QT; ++t) {
        const float dx = aqs[0][t] - a0;
        const float dy = aqs[1][t] - a1;
        const float dz = aqs[2][t] - a2;
        s[qq][t] -= spw * sqrtf(dx * dx + dy * dy + dz * dz) + pen;
      }
      *(float4*)&pt[j][0] = make_float4(s[qq][0], s[qq][1], s[qq][2], s[qq][3]);
      *(float4*)&pt[j][4] = make_float4(s[qq][4], s[qq][5], s[qq][6], s[qq][7]);
    }
  }
  __syncthreads();

  // phase 2: softmax — wave-pair per row-group of 4, float4 accesses
  {
    const int wid = tid >> 6, lane = tid & 63;
    const int g = wid >> 1, sw = wid & 1;
    float4 m4 = make_float4(-1e30f, -1e30f, -1e30f, -1e30f);
    for (int p = 0; p < 8; ++p) {
      const int j = lane + 64 * sw + 128 * p;
      const float4 t = *(const float4*)&pt[j][g * 4];
      m4.x = fmaxf(m4.x, t.x); m4.y = fmaxf(m4.y, t.y);
      m4.z = fmaxf(m4.z, t.z); m4.w = fmaxf(m4.w, t.w);
    }
#pragma unroll
    for (int off = 32; off; off >>= 1) {
      m4.x = fmaxf(m4.x, __shfl_xor(m4.x, off));
      m4.y = fmaxf(m4.y, __shfl_xor(m4.y, off));
      m4.z = fmaxf(m4.z, __shfl_xor(m4.z, off));
      m4.w = fmaxf(m4.w, __shfl_xor(m4.w, off));
    }
    if (lane == 0) {
      red_m[g][sw][0] = m4.x; red_m[g][sw][1] = m4.y;
      red_m[g][sw][2] = m4.z; red_m[g][sw][3] = m4.w;
    }
    __syncthreads();
    float4 mm;
    mm.x = fmaxf(red_m[g][0][0], red_m[g][1][0]);
    mm.y = fmaxf(red_m[g][0][1], red_m[g][1][1]);
    mm.z = fmaxf(red_m[g][0][2], red_m[g][1][2]);
    mm.w = fmaxf(red_m[g][0][3], red_m[g][1][3]);
    float4 s4 = make_float4(0.f, 0.f, 0.f, 0.f);
    for (int p = 0; p < 8; ++p) {
      const int j = lane + 64 * sw + 128 * p;
      float4 t = *(float4*)&pt[j][g * 4];
      t.x = __expf(t.x - mm.x); t.y = __expf(t.y - mm.y);
      t.z = __expf(t.z - mm.z); t.w = __expf(t.w - mm.w);
      *(float4*)&pt[j][g * 4] = t;
      s4.x += t.x; s4.y += t.y; s4.z += t.z; s4.w += t.w;
    }
#pragma unroll
    for (int off = 32; off; off >>= 1) {
      s4.x += __shfl_xor(s4.x, off);
      s4.y += __shfl_xor(s4.y, off);
      s4.z += __shfl_xor(s4.z, off);
      s4.w += __shfl_xor(s4.w, off);
    }
    if (lane == 0) {
      red_s[g][sw][0] = s4.x; red_s[g][sw][1] = s4.y;
      red_s[g][sw][2] = s4.z; red_s[g][sw][3] = s4.w;
    }
    __syncthreads();
    if (tid < QT) {
      const int gg = tid >> 2, c = tid & 3;
      rinv[tid] = 1.0f / (red_s[gg][0][c] + red_s[gg][1][c]);
    }
  }
  __syncthreads();

  // phase 3: weighted sums
  {
    const int rg  = tid >> 7;
    const int dim = tid & 127;
    if (dim < 103) {
      const float* src;
      int stride;
      if (dim < 64)       { src = v   + (size_t)bh * NL * NHD + dim;         stride = NHD; }
      else if (dim < 100) { src = vv  + (size_t)bh * NL * NV3 + (dim - 64);  stride = NV3; }
      else                { src = avp + (size_t)bh * NL * 3   + (dim - 100); stride = 3; }
      const int r0 = rg * 4;
      float a0 = 0.f, a1 = 0.f, a2 = 0.f, a3 = 0.f;
#pragma unroll 8
      for (int j = 0; j < NL; ++j) {
        const float sv = src[(size_t)j * stride];
        const float4 pv = *(const float4*)&pt[j][r0];
        a0 = fmaf(pv.x, sv, a0);
        a1 = fmaf(pv.y, sv, a1);
        a2 = fmaf(pv.z, sv, a2);
        a3 = fmaf(pv.w, sv, a3);
      }
      float accs[4] = {a0, a1, a2, a3};
#pragma unroll
      for (int i = 0; i < 4; ++i) {
        const int r = r0 + i;
        const float val = accs[i] * rinv[r];
        const int row = i0 + r;
        if (dim < 64)       catb[((size_t)b * NL + row) * KF + h * NHD + dim] = f2bf(val);
        else if (dim < 100) vacc[r][dim - 64] = val;
        else                aacc[r][dim - 100] = val;
      }
    }
  }
  __syncthreads();

  // phase 4: output-side rotation (R^T) -> catb cols [512,800) and [800,824)
  for (int u = tid; u < QT * 39; u += 256) {
    const int r = u / 39, w39 = u % 39;
    const size_t l = (size_t)b * NL + i0 + r;
    const float* R = rots + l * 9;
    if (w39 < NV3) {
      const int n = w39 % 3;
      const int base = w39 - n;
      const float val = vacc[r][base]     * R[0 * 3 + n]
                      + vacc[r][base + 1] * R[1 * 3 + n]
                      + vacc[r][base + 2] * R[2 * 3 + n];
      catb[l * KF + 512 + h * NV3 + w39] = f2bf(val);
    } else {
      const int n = w39 - NV3;
      const float c0 = aacc[r][0] - trans[l * 3 + 0];
      const float c1 = aacc[r][1] - trans[l * 3 + 1];
      const float c2 = aacc[r][2] - trans[l * 3 + 2];
      const float val = c0 * R[0 * 3 + n] + c1 * R[1 * 3 + n] + c2 * R[2 * 3 + n];
      catb[l * KF + 800 + h * 3 + n] = f2bf(val);
    }
  }
  // zero the K-pad columns 824..831
  if (tid < QT * 8) {
    const int r = tid >> 3;
    catb[((size_t)b * NL + i0 + r) * KF + 824 + (tid & 7)] = 0;
  }
}

} // namespace

extern "C" void kernel_launch(void* const* d_in, const int* in_sizes, int n_in,
                              void* d_out, int out_size, void* d_ws, size_t ws_size,
                              hipStream_t stream)
{
  const float* x       = (const float*)d_in[0];
  const float* mask    = (const float*)d_in[1];
  const float* rots    = (const float*)d_in[2];
  const float* trans   = (const float*)d_in[3];
  const float* w_q     = (const float*)d_in[4];
  const float* w_k     = (const float*)d_in[5];
  const float* w_v     = (const float*)d_in[6];
  const float* w_o     = (const float*)d_in[7];
  const float* w_vq_w  = (const float*)d_in[8];
  const float* w_vq_b  = (const float*)d_in[9];
  const float* w_vk_w  = (const float*)d_in[10];
  const float* w_vk_b  = (const float*)d_in[11];
  const float* w_vv_w  = (const float*)d_in[12];
  const float* w_vv_b  = (const float*)d_in[13];
  const float* w_vo_w  = (const float*)d_in[14];
  const float* w_vo_b  = (const float*)d_in[15];
  const float* w_aq_w  = (const float*)d_in[16];
  const float* w_aq_b  = (const float*)d_in[17];
  const float* w_av_w  = (const float*)d_in[18];
  const float* w_av_b  = (const float*)d_in[19];
  const float* w_ao_w  = (const float*)d_in[20];
  const float* w_ao_b  = (const float*)d_in[21];
  const float* aff_w   = (const float*)d_in[22];
  float* out = (float*)d_out;

  // Workspace layout with aliasing (~43 MB):
  //   regionA (9.44MB): [xh|xl|wch|wcl] before k_mm; [q|k_t] after (k_rope).
  //   Y (21MB fp32): projection output; catb (3.4MB bf16) overlays it after
  //   k_rope/k_rot have consumed Y (k_attn writes catb; stream-ordered).
  char* base = (char*)d_ws;
  ushort* xh  = (ushort*)base;                          // 2 MB
  ushort* xl  = xh + (size_t)2048 * 512;                // 2 MB
  ushort* wch = xl + (size_t)2048 * 512;                // 2.5 MB
  ushort* wcl = wch + (size_t)2560 * 512;               // 2.5 MB
  float*  q   = (float*)base;                           // 4 MB (over xh+xl)
  float*  k_t = q + (size_t)16 * 1024 * 64;             // 4 MB (over wch+wcl)
  char* p = base + 9437184;
  ushort* wcat2 = (ushort*)p; p += (size_t)512 * 832 * 2;
  float*  Y     = (float*)p;
  ushort* catb  = (ushort*)Y;                           // overlays Y
  p += (size_t)2048 * 2560 * 4;
  float*  v     = (float*)p;  p += (size_t)16 * 1024 * 64 * 4;
  float*  vq    = (float*)p;  p += (size_t)16 * 1024 * 36 * 4;
  float*  vk_t  = (float*)p;  p += (size_t)16 * 1024 * 36 * 4;
  float*  vv    = (float*)p;  p += (size_t)16 * 1024 * 36 * 4;
  float*  aq_t  = (float*)p;  p += (size_t)16 * 1024 * 3 * 4;
  float*  avp   = (float*)p;  p += (size_t)16 * 1024 * 3 * 4;

  k_pack<<<dim3(40, 13, 2), 256, 0, stream>>>(w_q, w_k, w_v, w_vq_w, w_vk_w,
                                              w_vv_w, w_aq_w, w_av_w,
                                              w_o, w_vo_w, w_ao_w,
                                              wch, wcl, wcat2);
  k_cvtx<<<1024, 256, 0, stream>>>(x, xh, xl);
  k_mm<<<dim3(16, 20), 256, 0, stream>>>(xh, xl, wch, wcl, Y, NCAT, 512);
  k_rope<<<dim3(32, 8), 256, 0, stream>>>(Y, q, k_t, v);
  k_rot<<<256, 256, 0, stream>>>(Y, rots, trans, w_vq_b, w_vk_b, w_vv_b,
                                 w_aq_b, w_av_b, vq, vk_t, vv, aq_t, avp);
  k_attn<<<2048, 256, 0, stream>>>(q, k_t, v, vq, vk_t, vv, aq_t, avp,
                                   mask, trans, rots, aff_w, catb);
  k_fin<<<dim3(16, 4), 256, 0, stream>>>(catb, wcat2, w_vo_b, w_ao_b, out);
}

// Round 7
// 188.027 us; speedup vs baseline: 7.0942x; 1.3772x over previous
//
#include <hip/hip_runtime.h>
#include <math.h>

namespace {

typedef __attribute__((ext_vector_type(8))) short short8;
typedef __attribute__((ext_vector_type(4))) float f32x4;

constexpr int NL  = 1024;
constexpr int ND  = 512;
constexpr int NH  = 8;
constexpr int NV3 = 36;
constexpr int NCAT = 2560;   // packed projection output cols (2448 used)
constexpr int KF   = 832;    // final-GEMM K (824 used)

constexpr float SCL_S = 0.044194173824159216f; // 1/sqrt(512)
constexpr float SCL_V = 1.0f / 6.0f;           // 1/sqrt(36)

__device__ inline ushort f2bf(float f) {
  uint u = __float_as_uint(f);
  u += 0x7FFFu + ((u >> 16) & 1u);
  return (ushort)(u >> 16);
}
__device__ inline float bf2f(ushort h) { return __uint_as_float((uint)h << 16); }

#define MFMA(a, b, c) __builtin_amdgcn_mfma_f32_16x16x32_bf16((a), (b), (c), 0, 0, 0)

// ---------------------------------------------------------------- k_pack
__global__ __launch_bounds__(256) void k_pack(
    const float* __restrict__ wq, const float* __restrict__ wk,
    const float* __restrict__ wv, const float* __restrict__ wvq,
    const float* __restrict__ wvk, const float* __restrict__ wvv,
    const float* __restrict__ waq, const float* __restrict__ wav,
    const float* __restrict__ w_o, const float* __restrict__ w_vo,
    const float* __restrict__ w_ao,
    ushort* __restrict__ wch, ushort* __restrict__ wcl,
    ushort* __restrict__ wcat2)
{
  __shared__ float t[64][65];
  const int tid = threadIdx.x;
  const int z = blockIdx.z;
  if (z == 0) { if (blockIdx.y >= 8) return; }
  else        { if (blockIdx.x >= 8) return; }
  const int n0 = blockIdx.x * 64, k0 = blockIdx.y * 64;
  const int rr = tid >> 6, cc = tid & 63;

  for (int p = 0; p < 16; ++p) {
    const int kk = k0 + p * 4 + rr;
    const int nn = n0 + cc;
    float val;
    if (z == 0) {
      if (nn < 1536) {
        const float* w = nn < 512 ? wq : (nn < 1024 ? wk : wv);
        val = w[(size_t)kk * 512 + (nn & 511)];
      } else if (nn < 2400) {
        const float* w = nn < 1824 ? wvq : (nn < 2112 ? wvk : wvv);
        val = w[(size_t)kk * 288 + (nn - 1536) % 288];
      } else if (nn < 2424) val = waq[(size_t)kk * 24 + nn - 2400];
      else if (nn < 2448)   val = wav[(size_t)kk * 24 + nn - 2424];
      else val = 0.f;
    } else {
      if (kk < 512)      val = w_o [(size_t)kk * 512 + nn];
      else if (kk < 800) val = w_vo[(size_t)(kk - 512) * 512 + nn];
      else if (kk < 824) val = w_ao[(size_t)(kk - 800) * 512 + nn];
      else val = 0.f;
    }
    t[p * 4 + rr][cc] = val;
  }
  __syncthreads();
  for (int p = 0; p < 16; ++p) {
    const int nn = p * 4 + rr;
    const int kk = cc;
    const float val = t[kk][nn];
    const ushort h16 = f2bf(val);
    if (z == 0) {
      wch[(size_t)(n0 + nn) * 512 + k0 + kk] = h16;
      wcl[(size_t)(n0 + nn) * 512 + k0 + kk] = f2bf(val - bf2f(h16));
    } else {
      wcat2[(size_t)(n0 + nn) * 832 + k0 + kk] = h16;
    }
  }
}

// ---------------------------------------------------------------- k_cvtx
__global__ __launch_bounds__(256) void k_cvtx(const float* __restrict__ x,
                                              ushort* __restrict__ xh,
                                              ushort* __restrict__ xl)
{
  const int i = (blockIdx.x * 256 + threadIdx.x) * 4;
  const float4 v = *(const float4*)&x[i];
  ushort4 h, l;
  h.x = f2bf(v.x); l.x = f2bf(v.x - bf2f(h.x));
  h.y = f2bf(v.y); l.y = f2bf(v.y - bf2f(h.y));
  h.z = f2bf(v.z); l.z = f2bf(v.z - bf2f(h.z));
  h.w = f2bf(v.w); l.w = f2bf(v.w - bf2f(h.w));
  *(ushort4*)&xh[i] = h;
  *(ushort4*)&xl[i] = l;
}

// ---------------------------------------------------------------- k_mm
__global__ __launch_bounds__(256) void k_mm(
    const ushort* __restrict__ Ah, const ushort* __restrict__ Al,
    const ushort* __restrict__ Bh, const ushort* __restrict__ Bl,
    float* __restrict__ Y, int N, int K)
{
  __shared__ __align__(16) ushort Ahs[128][40];
  __shared__ __align__(16) ushort Als[128][40];
  __shared__ __align__(16) ushort Bhs[128][40];
  __shared__ __align__(16) ushort Bls[128][40];
  const int tid = threadIdx.x;
  const int m0 = blockIdx.x * 128, n0 = blockIdx.y * 128;
  const int w = tid >> 6, lane = tid & 63;
  const int wm = (w & 1) * 64, wn = (w >> 1) * 64;
  const int fr = lane & 15, fg = lane >> 4;

  f32x4 acc[4][4];
#pragma unroll
  for (int i = 0; i < 4; ++i)
#pragma unroll
    for (int j = 0; j < 4; ++j) acc[i][j] = (f32x4){0.f, 0.f, 0.f, 0.f};

  const int sr = tid >> 1, sk = (tid & 1) * 16;
  const ushort* agh = Ah + (size_t)(m0 + sr) * K + sk;
  const ushort* agl = Al + (size_t)(m0 + sr) * K + sk;
  const ushort* bgh = Bh + (size_t)(n0 + sr) * K + sk;
  const ushort* bgl = Bl + (size_t)(n0 + sr) * K + sk;
  short8 pah0 = *(const short8*)agh, pah1 = *(const short8*)(agh + 8);
  short8 pal0 = *(const short8*)agl, pal1 = *(const short8*)(agl + 8);
  short8 pbh0 = *(const short8*)bgh, pbh1 = *(const short8*)(bgh + 8);
  short8 pbl0 = *(const short8*)bgl, pbl1 = *(const short8*)(bgl + 8);

  const int NT = K >> 5;
  for (int kt = 0; kt < NT; ++kt) {
    __syncthreads();
    *(short8*)&Ahs[sr][sk] = pah0; *(short8*)&Ahs[sr][sk + 8] = pah1;
    *(short8*)&Als[sr][sk] = pal0; *(short8*)&Als[sr][sk + 8] = pal1;
    *(short8*)&Bhs[sr][sk] = pbh0; *(short8*)&Bhs[sr][sk + 8] = pbh1;
    *(short8*)&Bls[sr][sk] = pbl0; *(short8*)&Bls[sr][sk + 8] = pbl1;
    __syncthreads();
    if (kt + 1 < NT) {
      const size_t off = (size_t)(kt + 1) * 32;
      pah0 = *(const short8*)(agh + off); pah1 = *(const short8*)(agh + off + 8);
      pal0 = *(const short8*)(agl + off); pal1 = *(const short8*)(agl + off + 8);
      pbh0 = *(const short8*)(bgh + off); pbh1 = *(const short8*)(bgh + off + 8);
      pbl0 = *(const short8*)(bgl + off); pbl1 = *(const short8*)(bgl + off + 8);
    }
    short8 fah[4], fal[4], fbh[4], fbl[4];
#pragma unroll
    for (int i = 0; i < 4; ++i) {
      fah[i] = *(const short8*)&Ahs[wm + i * 16 + fr][fg * 8];
      fal[i] = *(const short8*)&Als[wm + i * 16 + fr][fg * 8];
    }
#pragma unroll
    for (int j = 0; j < 4; ++j) {
      fbh[j] = *(const short8*)&Bhs[wn + j * 16 + fr][fg * 8];
      fbl[j] = *(const short8*)&Bls[wn + j * 16 + fr][fg * 8];
    }
#pragma unroll
    for (int i = 0; i < 4; ++i)
#pragma unroll
      for (int j = 0; j < 4; ++j) {
        f32x4 t = MFMA(fah[i], fbh[j], acc[i][j]);
        t = MFMA(fal[i], fbh[j], t);
        t = MFMA(fah[i], fbl[j], t);
        acc[i][j] = t;
      }
  }

  const int rb = fg * 4;
#pragma unroll
  for (int i = 0; i < 4; ++i)
#pragma unroll
    for (int j = 0; j < 4; ++j) {
      const int n = n0 + wn + j * 16 + fr;
#pragma unroll
      for (int r = 0; r < 4; ++r) {
        const int m = m0 + wm + i * 16 + rb + r;
        Y[(size_t)m * N + n] = acc[i][j][r];
      }
    }
}

// ---------------------------------------------------------------- k_fin
__global__ __launch_bounds__(256) void k_fin(
    const ushort* __restrict__ A, const ushort* __restrict__ Bt,
    const float* __restrict__ b_vo, const float* __restrict__ b_ao,
    float* __restrict__ out)
{
  __shared__ __align__(16) ushort As[128][40];
  __shared__ __align__(16) ushort Bs[128][40];
  const int tid = threadIdx.x;
  const int m0 = blockIdx.x * 128, n0 = blockIdx.y * 128;
  const int w = tid >> 6, lane = tid & 63;
  const int wm = (w & 1) * 64, wn = (w >> 1) * 64;
  const int fr = lane & 15, fg = lane >> 4;
  const int K = KF;

  f32x4 acc[4][4];
#pragma unroll
  for (int i = 0; i < 4; ++i)
#pragma unroll
    for (int j = 0; j < 4; ++j) acc[i][j] = (f32x4){0.f, 0.f, 0.f, 0.f};

  const int sr = tid >> 1, sk = (tid & 1) * 16;
  const ushort* ag = A + (size_t)(m0 + sr) * K + sk;
  const ushort* bg = Bt + (size_t)(n0 + sr) * K + sk;
  short8 a0 = *(const short8*)ag;
  short8 a1 = *(const short8*)(ag + 8);
  short8 b0 = *(const short8*)bg;
  short8 b1 = *(const short8*)(bg + 8);

  const int NT = K >> 5;
  for (int kt = 0; kt < NT; ++kt) {
    __syncthreads();
    *(short8*)&As[sr][sk] = a0; *(short8*)&As[sr][sk + 8] = a1;
    *(short8*)&Bs[sr][sk] = b0; *(short8*)&Bs[sr][sk + 8] = b1;
    __syncthreads();
    if (kt + 1 < NT) {
      const ushort* agn = ag + (size_t)(kt + 1) * 32;
      const ushort* bgn = bg + (size_t)(kt + 1) * 32;
      a0 = *(const short8*)agn; a1 = *(const short8*)(agn + 8);
      b0 = *(const short8*)bgn; b1 = *(const short8*)(bgn + 8);
    }
    short8 aF[4], bF[4];
#pragma unroll
    for (int i = 0; i < 4; ++i) aF[i] = *(const short8*)&As[wm + i * 16 + fr][fg * 8];
#pragma unroll
    for (int j = 0; j < 4; ++j) bF[j] = *(const short8*)&Bs[wn + j * 16 + fr][fg * 8];
#pragma unroll
    for (int i = 0; i < 4; ++i)
#pragma unroll
      for (int j = 0; j < 4; ++j)
        acc[i][j] = MFMA(aF[i], bF[j], acc[i][j]);
  }

  const int rb = fg * 4;
#pragma unroll
  for (int j = 0; j < 4; ++j) {
    const int n = n0 + wn + j * 16 + fr;
    const float bias = b_vo[n] + b_ao[n];
#pragma unroll
    for (int i = 0; i < 4; ++i)
#pragma unroll
      for (int r = 0; r < 4; ++r) {
        const int m = m0 + wm + i * 16 + rb + r;
        out[(size_t)m * ND + n] = acc[i][j][r] + bias;
      }
  }
}

// ---------------------------------------------------------------- k_rope
__global__ __launch_bounds__(256) void k_rope(
    const float* __restrict__ Y,
    ushort* __restrict__ qAh, ushort* __restrict__ qAl,
    ushort* __restrict__ kBh, ushort* __restrict__ kBl,
    ushort* __restrict__ Vt)
{
  __shared__ float t0[64][65];
  __shared__ float t1[64][72];
  const int tid = threadIdx.x;
  const int l0 = blockIdx.x * 64, h = blockIdx.y;
  const int b = l0 >> 10, ll0 = l0 & 1023;
  const int bh = b * NH + h;
  const int rr = tid >> 6, cc = tid & 63;
  const float inv = powf(10000.f, -(float)(cc & ~1) / 64.f);
  const bool odd = (cc & 1) != 0;

  // ---- q ----
  for (int p = 0; p < 16; ++p) {
    const int r = p * 4 + rr;
    t0[r][cc] = Y[(size_t)(l0 + r) * NCAT + h * 64 + cc];
  }
  __syncthreads();
  for (int p = 0; p < 16; ++p) {
    const int r = p * 4 + rr;
    float sv, cv;
    __sincosf((float)(ll0 + r) * inv, &sv, &cv);
    const float e = t0[r][cc & ~1], o = t0[r][(cc & ~1) + 1];
    const float val = (odd ? fmaf(e, sv, o * cv) : fmaf(e, cv, -o * sv)) * SCL_S;
    const size_t row = ((size_t)bh * NL + ll0 + r) * 128 + cc;
    const ushort hi = f2bf(val);
    qAh[row] = hi;
    qAl[row] = f2bf(val - bf2f(hi));
  }
  __syncthreads();
  // ---- k ----
  for (int p = 0; p < 16; ++p) {
    const int r = p * 4 + rr;
    t0[r][cc] = Y[(size_t)(l0 + r) * NCAT + 512 + h * 64 + cc];
  }
  __syncthreads();
  for (int p = 0; p < 16; ++p) {
    const int r = p * 4 + rr;
    float sv, cv;
    __sincosf((float)(ll0 + r) * inv, &sv, &cv);
    const float e = t0[r][cc & ~1], o = t0[r][(cc & ~1) + 1];
    const float val = odd ? fmaf(e, sv, o * cv) : fmaf(e, cv, -o * sv);
    const size_t row = ((size_t)bh * NL + ll0 + r) * 128 + cc;
    const ushort hi = f2bf(val);
    kBh[row] = hi;
    kBl[row] = f2bf(val - bf2f(hi));
  }
  // ---- v (transpose to Vt[dim][token]) ----
  for (int p = 0; p < 16; ++p) {
    const int r = p * 4 + rr;
    t1[cc][r] = Y[(size_t)(l0 + r) * NCAT + 1024 + h * 64 + cc];
  }
  __syncthreads();
  for (int p = 0; p < 16; ++p) {
    const int hd = p * 4 + rr;
    Vt[((size_t)bh * 112 + hd) * NL + ll0 + cc] = f2bf(t1[hd][cc]);
  }
  // zero Vt pad rows 103..111
  for (int u = tid; u < 9 * 64; u += 256)
    Vt[((size_t)bh * 112 + 103 + (u >> 6)) * NL + ll0 + (u & 63)] = 0;
}

// ---------------------------------------------------------------- k_rot
__global__ __launch_bounds__(256) void k_rot(
    const float* __restrict__ Y,
    const float* __restrict__ rots, const float* __restrict__ trans,
    const float* __restrict__ mask,
    const float* __restrict__ bvq, const float* __restrict__ bvk,
    const float* __restrict__ bvv, const float* __restrict__ baq,
    const float* __restrict__ bav,
    ushort* __restrict__ qAh, ushort* __restrict__ qAl,
    ushort* __restrict__ kBh, ushort* __restrict__ kBl,
    ushort* __restrict__ Vt,
    float* __restrict__ aq_t, float* __restrict__ penc)
{
  __shared__ float ys[8][912];
  const int tb = blockIdx.x * 8;
  const int b = tb >> 10;
  const int tid = threadIdx.x;

  for (int t = 0; t < 8; ++t)
    for (int n = tid; n < 912; n += 256)
      ys[t][n] = Y[(size_t)(tb + t) * NCAT + 1536 + n];
  __syncthreads();

  // vq -> qA cols 64..99 ; vk -> kB cols 64..99 ; vv -> Vt rows 64..99
  for (int u = tid; u < 8 * 288; u += 256) {
    const int t = u / 288, n = u % 288;
    const int l = tb + t, ll = l & (NL - 1);
    const int c = n % 3, base = n - c;
    const int h = n / NV3, m = n % NV3;
    const float r0 = rots[(size_t)l * 9 + c * 3 + 0];
    const float r1 = rots[(size_t)l * 9 + c * 3 + 1];
    const float r2 = rots[(size_t)l * 9 + c * 3 + 2];
    const float vqv = (r0 * (ys[t][base] + bvq[base])
                     + r1 * (ys[t][base + 1] + bvq[base + 1])
                     + r2 * (ys[t][base + 2] + bvq[base + 2])) * SCL_V;
    const float vkv = r0 * (ys[t][288 + base] + bvk[base])
                    + r1 * (ys[t][289 + base] + bvk[base + 1])
                    + r2 * (ys[t][290 + base] + bvk[base + 2]);
    const float vvv = r0 * (ys[t][576 + base] + bvv[base])
                    + r1 * (ys[t][577 + base] + bvv[base + 1])
                    + r2 * (ys[t][578 + base] + bvv[base + 2]);
    const size_t row = ((size_t)(b * NH + h) * NL + ll) * 128 + 64 + m;
    ushort hi = f2bf(vqv);
    qAh[row] = hi; qAl[row] = f2bf(vqv - bf2f(hi));
    hi = f2bf(vkv);
    kBh[row] = hi; kBl[row] = f2bf(vkv - bf2f(hi));
    Vt[((size_t)(b * NH + h) * 112 + 64 + m) * NL + ll] = f2bf(vvv);
  }
  // zero qA cols 100..127
  for (int u = tid; u < 8 * 8 * 14; u += 256) {
    const int t = u / 112, rem = u % 112, h = rem / 14, k = rem % 14;
    const int ll = (tb + t) & (NL - 1);
    const size_t row = ((size_t)(b * NH + h) * NL + ll) * 128 + 100 + 2 * k;
    *(uint*)&qAh[row] = 0;
    *(uint*)&qAl[row] = 0;
  }
  // aq (exact fp32, transposed) + zero kB pad cols 100..127
  for (int u = tid; u < 64; u += 256) {
    const int t = u >> 3, h = u & 7;
    const int l = tb + t, ll = l & (NL - 1);
    const int base = h * 3;
    const size_t tok = (size_t)(b * NH + h) * NL + ll;
#pragma unroll
    for (int c = 0; c < 3; ++c) {
      const float aqv =
          rots[(size_t)l * 9 + c * 3 + 0] * (ys[t][864 + base] + baq[base])
        + rots[(size_t)l * 9 + c * 3 + 1] * (ys[t][865 + base] + baq[base + 1])
        + rots[(size_t)l * 9 + c * 3 + 2] * (ys[t][866 + base] + baq[base + 2])
        + trans[(size_t)l * 3 + c];
      aq_t[((size_t)(b * NH + h) * 3 + c) * NL + ll] = aqv;
    }
#pragma unroll
    for (int k = 0; k < 14; ++k) {
      *(uint*)&kBh[tok * 128 + 100 + 2 * k] = 0;
      *(uint*)&kBl[tok * 128 + 100 + 2 * k] = 0;
    }
  }
  // av -> Vt rows 100..102
  for (int u = tid; u < 8 * 24; u += 256) {
    const int t = u / 24, n = u % 24;
    const int l = tb + t, ll = l & (NL - 1);
    const int c = n % 3, h = n / 3, base = h * 3;
    const float val = rots[(size_t)l * 9 + c * 3 + 0] * (ys[t][888 + base] + bav[base])
                    + rots[(size_t)l * 9 + c * 3 + 1] * (ys[t][889 + base] + bav[base + 1])
                    + rots[(size_t)l * 9 + c * 3 + 2] * (ys[t][890 + base] + bav[base + 2])
                    + trans[(size_t)l * 3 + c];
    Vt[((size_t)(b * NH + h) * 112 + 100 + c) * NL + ll] = f2bf(val);
  }
  // penalty
  for (int u = tid; u < 8; u += 256) {
    const int ll = (tb + u) & (NL - 1);
    penc[(size_t)b * NL + ll] = 1e6f * (1.0f - mask[(size_t)b * NL + ll]);
  }
}

// ---------------------------------------------------------------- k_attn
// Flash MFMA attention; distances exact fp32 in the epilogue.
__global__ __launch_bounds__(256) void k_attn(
    const ushort* __restrict__ qAh, const ushort* __restrict__ qAl,
    const ushort* __restrict__ kBh, const ushort* __restrict__ kBl,
    const ushort* __restrict__ Vt,
    const float* __restrict__ aq_t, const float* __restrict__ penc,
    const float* __restrict__ rots, const float* __restrict__ trans,
    const float* __restrict__ affw,
    ushort* __restrict__ catb)
{
  __shared__ __align__(16) ushort qh_s[32][128];
  __shared__ __align__(16) ushort ql_s[32][128];
  __shared__ __align__(16) ushort P_s[4][16][72];
  __shared__ float Ocmb[2][16][112];
  __shared__ float mst[2][16], lst[2][16];
  __shared__ float aqi_s[3][32];

  const int bh = blockIdx.y;
  const int b = bh >> 3, h = bh & 7;
  const int i0 = blockIdx.x * 32;
  const int tid = threadIdx.x;
  const int w = tid >> 6, lane = tid & 63;
  const int rg = w >> 1, jh = w & 1;
  const int fr = lane & 15, fg = lane >> 4;

  for (int u = tid; u < 512; u += 256) {
    const int r = u >> 4, c = (u & 15) * 8;
    *(short8*)&qh_s[r][c] = *(const short8*)&qAh[((size_t)bh * NL + i0 + r) * 128 + c];
    *(short8*)&ql_s[r][c] = *(const short8*)&qAl[((size_t)bh * NL + i0 + r) * 128 + c];
  }
  if (tid < 96) {
    const int c = tid >> 5, i = tid & 31;
    aqi_s[c][i] = aq_t[((size_t)bh * 3 + c) * NL + i0 + i];
  }
  __syncthreads();

  const float spw = logf(1.0f + expf(affw[h]));

  short8 aQh[4], aQl[4];
#pragma unroll
  for (int ks = 0; ks < 4; ++ks) {
    aQh[ks] = *(const short8*)&qh_s[rg * 16 + fr][ks * 32 + fg * 8];
    aQl[ks] = *(const short8*)&ql_s[rg * 16 + fr][ks * 32 + fg * 8];
  }

  float ai0[4], ai1[4], ai2[4];
#pragma unroll
  for (int r_ = 0; r_ < 4; ++r_) {
    const int row = rg * 16 + fg * 4 + r_;
    ai0[r_] = aqi_s[0][row];
    ai1[r_] = aqi_s[1][row];
    ai2[r_] = aqi_s[2][row];
  }

  float mrun[4], lrun[4];
#pragma unroll
  for (int r_ = 0; r_ < 4; ++r_) { mrun[r_] = -3.0e38f; lrun[r_] = 0.f; }

  f32x4 accO[7];
#pragma unroll
  for (int ct = 0; ct < 7; ++ct) accO[ct] = (f32x4){0.f, 0.f, 0.f, 0.f};

  const size_t kbase = (size_t)bh * NL * 128;
  const size_t vbase = (size_t)bh * 112 * NL;
  const float* aqx = aq_t + (size_t)bh * 3 * NL;

  for (int jt = 0; jt < 8; ++jt) {
    const int j0 = jh * 512 + jt * 64;

    f32x4 accS[4];
#pragma unroll
    for (int ct = 0; ct < 4; ++ct) accS[ct] = (f32x4){0.f, 0.f, 0.f, 0.f};
#pragma unroll
    for (int ct = 0; ct < 4; ++ct) {
      const size_t rowb = kbase + (size_t)(j0 + ct * 16 + fr) * 128;
#pragma unroll
      for (int ks = 0; ks < 4; ++ks) {
        const short8 bh8 = *(const short8*)&kBh[rowb + ks * 32 + fg * 8];
        const short8 bl8 = *(const short8*)&kBl[rowb + ks * 32 + fg * 8];
        f32x4 t = MFMA(aQh[ks], bh8, accS[ct]);
        t = MFMA(aQl[ks], bh8, t);
        t = MFMA(aQh[ks], bl8, t);
        accS[ct] = t;
      }
    }

    // epilogue: exact fp32 distances + penalty, online softmax
    float pvals[4][4];
    float smax[4] = {-3.0e38f, -3.0e38f, -3.0e38f, -3.0e38f};
#pragma unroll
    for (int ct = 0; ct < 4; ++ct) {
      const int j = j0 + ct * 16 + fr;
      const float aj0 = aqx[j];
      const float aj1 = aqx[NL + j];
      const float aj2v = aqx[2 * NL + j];
      const float pen = penc[(size_t)b * NL + j];
#pragma unroll
      for (int r_ = 0; r_ < 4; ++r_) {
        const float dx = ai0[r_] - aj0;
        const float dy = ai1[r_] - aj1;
        const float dz = ai2[r_] - aj2v;
        const float s = accS[ct][r_]
                      - spw * sqrtf(dx * dx + dy * dy + dz * dz) - pen;
        pvals[ct][r_] = s;
        smax[r_] = fmaxf(smax[r_], s);
      }
    }
#pragma unroll
    for (int off = 1; off < 16; off <<= 1) {
#pragma unroll
      for (int r_ = 0; r_ < 4; ++r_)
        smax[r_] = fmaxf(smax[r_], __shfl_xor(smax[r_], off));
    }
    float scale[4], lsum[4];
#pragma unroll
    for (int r_ = 0; r_ < 4; ++r_) {
      const float mnew = fmaxf(mrun[r_], smax[r_]);
      scale[r_] = __expf(mrun[r_] - mnew);
      mrun[r_] = mnew;
      lsum[r_] = 0.f;
    }
#pragma unroll
    for (int ct = 0; ct < 4; ++ct)
#pragma unroll
      for (int r_ = 0; r_ < 4; ++r_) {
        const float p = __expf(pvals[ct][r_] - mrun[r_]);
        pvals[ct][r_] = p;
        lsum[r_] += p;
      }
#pragma unroll
    for (int off = 1; off < 16; off <<= 1) {
#pragma unroll
      for (int r_ = 0; r_ < 4; ++r_) lsum[r_] += __shfl_xor(lsum[r_], off);
    }
#pragma unroll
    for (int r_ = 0; r_ < 4; ++r_) lrun[r_] = lrun[r_] * scale[r_] + lsum[r_];
#pragma unroll
    for (int ct = 0; ct < 7; ++ct)
#pragma unroll
      for (int r_ = 0; r_ < 4; ++r_) accO[ct][r_] *= scale[r_];

#pragma unroll
    for (int ct = 0; ct < 4; ++ct)
#pragma unroll
      for (int r_ = 0; r_ < 4; ++r_)
        P_s[w][fg * 4 + r_][ct * 16 + fr] = f2bf(pvals[ct][r_]);
    __syncthreads();

    // PV
    short8 aP0 = *(const short8*)&P_s[w][fr][fg * 8];
    short8 aP1 = *(const short8*)&P_s[w][fr][32 + fg * 8];
#pragma unroll
    for (int ct = 0; ct < 7; ++ct) {
      const size_t vrow = vbase + (size_t)(ct * 16 + fr) * NL + j0;
      const short8 b0 = *(const short8*)&Vt[vrow + fg * 8];
      const short8 b1 = *(const short8*)&Vt[vrow + 32 + fg * 8];
      f32x4 t = MFMA(aP0, b0, accO[ct]);
      accO[ct] = MFMA(aP1, b1, t);
    }
  }

  // combine the two j-halves per row-group
  if (jh == 0) {
#pragma unroll
    for (int ct = 0; ct < 7; ++ct)
#pragma unroll
      for (int r_ = 0; r_ < 4; ++r_)
        Ocmb[rg][fg * 4 + r_][ct * 16 + fr] = accO[ct][r_];
    if (fr == 0) {
#pragma unroll
      for (int r_ = 0; r_ < 4; ++r_) {
        mst[rg][fg * 4 + r_] = mrun[r_];
        lst[rg][fg * 4 + r_] = lrun[r_];
      }
    }
  }
  __syncthreads();
  if (jh == 1) {
    float fac0[4], fac1[4];
#pragma unroll
    for (int r_ = 0; r_ < 4; ++r_) {
      const float m0 = mst[rg][fg * 4 + r_];
      const float l0 = lst[rg][fg * 4 + r_];
      const float M = fmaxf(m0, mrun[r_]);
      const float s0 = __expf(m0 - M), s1 = __expf(mrun[r_] - M);
      const float inv = 1.0f / (l0 * s0 + lrun[r_] * s1);
      fac0[r_] = s0 * inv; fac1[r_] = s1 * inv;
    }
#pragma unroll
    for (int ct = 0; ct < 7; ++ct)
#pragma unroll
      for (int r_ = 0; r_ < 4; ++r_)
        Ocmb[rg][fg * 4 + r_][ct * 16 + fr] =
            Ocmb[rg][fg * 4 + r_][ct * 16 + fr] * fac0[r_] + accO[ct][r_] * fac1[r_];
  }
  __syncthreads();

  // epilogue: rotations + catb writes
  for (int u = tid; u < 32 * 103; u += 256) {
    const int lr = u / 103, d = u % 103;
    const int gi = i0 + lr;
    const size_t gl = (size_t)b * NL + gi;
    const float* O = Ocmb[lr >> 4][lr & 15];
    float val;
    int col;
    if (d < 64) {
      val = O[d];
      col = h * 64 + d;
    } else if (d < 100) {
      const int v3 = d - 64;
      const int n = v3 % 3;
      const int base = 64 + v3 - n;
      val = O[base] * rots[gl * 9 + n] + O[base + 1] * rots[gl * 9 + 3 + n]
          + O[base + 2] * rots[gl * 9 + 6 + n];
      col = 512 + h * NV3 + v3;
    } else {
      const int n = d - 100;
      const float c0 = O[100] - trans[gl * 3 + 0];
      const float c1 = O[101] - trans[gl * 3 + 1];
      const float c2 = O[102] - trans[gl * 3 + 2];
      val = c0 * rots[gl * 9 + n] + c1 * rots[gl * 9 + 3 + n] + c2 * rots[gl * 9 + 6 + n];
      col = 800 + h * 3 + n;
    }
    catb[gl * KF + col] = f2bf(val);
  }
  if (h == 0) {
    for (int u = tid; u < 32 * 8; u += 256)
      catb[((size_t)b * NL + i0 + (u >> 3)) * KF + 824 + (u & 7)] = 0;
  }
}

} // namespace

extern "C" void kernel_launch(void* const* d_in, const int* in_sizes, int n_in,
                              void* d_out, int out_size, void* d_ws, size_t ws_size,
                              hipStream_t stream)
{
  const float* x       = (const float*)d_in[0];
  const float* mask    = (const float*)d_in[1];
  const float* rots    = (const float*)d_in[2];
  const float* trans   = (const float*)d_in[3];
  const float* w_q     = (const float*)d_in[4];
  const float* w_k     = (const float*)d_in[5];
  const float* w_v     = (const float*)d_in[6];
  const float* w_o     = (const float*)d_in[7];
  const float* w_vq_w  = (const float*)d_in[8];
  const float* w_vq_b  = (const float*)d_in[9];
  const float* w_vk_w  = (const float*)d_in[10];
  const float* w_vk_b  = (const float*)d_in[11];
  const float* w_vv_w  = (const float*)d_in[12];
  const float* w_vv_b  = (const float*)d_in[13];
  const float* w_vo_w  = (const float*)d_in[14];
  const float* w_vo_b  = (const float*)d_in[15];
  const float* w_aq_w  = (const float*)d_in[16];
  const float* w_aq_b  = (const float*)d_in[17];
  const float* w_av_w  = (const float*)d_in[18];
  const float* w_av_b  = (const float*)d_in[19];
  const float* w_ao_w  = (const float*)d_in[20];
  const float* w_ao_b  = (const float*)d_in[21];
  const float* aff_w   = (const float*)d_in[22];
  float* out = (float*)d_out;

  // workspace (~41.4 MiB), aliased:
  //  region A (9.44 MB): xh|xl|wch|wcl (k_mm inputs) -> qAh|qAl|aq_t after k_mm
  //  Y (21 MB): projections -> catb (3.4 MB) overlays after k_rope/k_rot
  char* base = (char*)d_ws;
  ushort* xh  = (ushort*)base;
  ushort* xl  = xh + (size_t)2048 * 512;
  ushort* wch = xl + (size_t)2048 * 512;
  ushort* wcl = wch + (size_t)2560 * 512;
  ushort* qAh = (ushort*)base;                       // 4 MB
  ushort* qAl = qAh + (size_t)16 * 1024 * 128;       // 4 MB
  float*  aq_t = (float*)(qAl + (size_t)16 * 1024 * 128);  // 196 KB (in old 1MB slot)
  char* p = base + 9437184;
  ushort* wcat2 = (ushort*)p; p += (size_t)512 * 832 * 2;
  float*  Y     = (float*)p;
  ushort* catb  = (ushort*)Y;
  p += (size_t)2048 * 2560 * 4;
  ushort* kBh = (ushort*)p; p += (size_t)16 * 1024 * 128 * 2;
  ushort* kBl = (ushort*)p; p += (size_t)16 * 1024 * 128 * 2;
  ushort* Vt  = (ushort*)p; p += (size_t)16 * 112 * 1024 * 2;
  float* penc = (float*)p;  p += (size_t)2048 * 4;

  k_pack<<<dim3(40, 13, 2), 256, 0, stream>>>(w_q, w_k, w_v, w_vq_w, w_vk_w,
                                              w_vv_w, w_aq_w, w_av_w,
                                              w_o, w_vo_w, w_ao_w,
                                              wch, wcl, wcat2);
  k_cvtx<<<1024, 256, 0, stream>>>(x, xh, xl);
  k_mm<<<dim3(16, 20), 256, 0, stream>>>(xh, xl, wch, wcl, Y, NCAT, 512);
  k_rope<<<dim3(32, 8), 256, 0, stream>>>(Y, qAh, qAl, kBh, kBl, Vt);
  k_rot<<<256, 256, 0, stream>>>(Y, rots, trans, mask,
                                 w_vq_b, w_vk_b, w_vv_b, w_aq_b, w_av_b,
                                 qAh, qAl, kBh, kBl, Vt, aq_t, penc);
  k_attn<<<dim3(32, 16), 256, 0, stream>>>(qAh, qAl, kBh, kBl, Vt,
                                           aq_t, penc, rots, trans, aff_w, catb);
  k_fin<<<dim3(16, 4), 256, 0, stream>>>(catb, wcat2, w_vo_b, w_ao_b, out);
}

// Round 8
// 184.974 us; speedup vs baseline: 7.2113x; 1.0165x over previous
//
#include <hip/hip_runtime.h>
#include <math.h>

namespace {

typedef __attribute__((ext_vector_type(8))) short short8;
typedef __attribute__((ext_vector_type(4))) float f32x4;

constexpr int NL  = 1024;
constexpr int ND  = 512;
constexpr int NH  = 8;
constexpr int NV3 = 36;
constexpr int NCAT = 2560;   // packed projection output cols (2448 used)
constexpr int KF   = 832;    // final-GEMM K (824 used)

constexpr float SCL_S = 0.044194173824159216f; // 1/sqrt(512)
constexpr float SCL_V = 1.0f / 6.0f;           // 1/sqrt(36)

__device__ inline ushort f2bf(float f) {
  uint u = __float_as_uint(f);
  u += 0x7FFFu + ((u >> 16) & 1u);
  return (ushort)(u >> 16);
}
__device__ inline float bf2f(ushort h) { return __uint_as_float((uint)h << 16); }

#define MFMA(a, b, c) __builtin_amdgcn_mfma_f32_16x16x32_bf16((a), (b), (c), 0, 0, 0)

// ---------------------------------------------------------------- k_pack
__global__ __launch_bounds__(256) void k_pack(
    const float* __restrict__ wq, const float* __restrict__ wk,
    const float* __restrict__ wv, const float* __restrict__ wvq,
    const float* __restrict__ wvk, const float* __restrict__ wvv,
    const float* __restrict__ waq, const float* __restrict__ wav,
    const float* __restrict__ w_o, const float* __restrict__ w_vo,
    const float* __restrict__ w_ao,
    ushort* __restrict__ wch, ushort* __restrict__ wcl,
    ushort* __restrict__ wcat2)
{
  __shared__ float t[64][65];
  const int tid = threadIdx.x;
  const int z = blockIdx.z;
  if (z == 0) { if (blockIdx.y >= 8) return; }
  else        { if (blockIdx.x >= 8) return; }
  const int n0 = blockIdx.x * 64, k0 = blockIdx.y * 64;
  const int rr = tid >> 6, cc = tid & 63;

  for (int p = 0; p < 16; ++p) {
    const int kk = k0 + p * 4 + rr;
    const int nn = n0 + cc;
    float val;
    if (z == 0) {
      if (nn < 1536) {
        const float* w = nn < 512 ? wq : (nn < 1024 ? wk : wv);
        val = w[(size_t)kk * 512 + (nn & 511)];
      } else if (nn < 2400) {
        const float* w = nn < 1824 ? wvq : (nn < 2112 ? wvk : wvv);
        val = w[(size_t)kk * 288 + (nn - 1536) % 288];
      } else if (nn < 2424) val = waq[(size_t)kk * 24 + nn - 2400];
      else if (nn < 2448)   val = wav[(size_t)kk * 24 + nn - 2424];
      else val = 0.f;
    } else {
      if (kk < 512)      val = w_o [(size_t)kk * 512 + nn];
      else if (kk < 800) val = w_vo[(size_t)(kk - 512) * 512 + nn];
      else if (kk < 824) val = w_ao[(size_t)(kk - 800) * 512 + nn];
      else val = 0.f;
    }
    t[p * 4 + rr][cc] = val;
  }
  __syncthreads();
  for (int p = 0; p < 16; ++p) {
    const int nn = p * 4 + rr;
    const int kk = cc;
    const float val = t[kk][nn];
    const ushort h16 = f2bf(val);
    if (z == 0) {
      wch[(size_t)(n0 + nn) * 512 + k0 + kk] = h16;
      wcl[(size_t)(n0 + nn) * 512 + k0 + kk] = f2bf(val - bf2f(h16));
    } else {
      wcat2[(size_t)(n0 + nn) * 832 + k0 + kk] = h16;
    }
  }
}

// ---------------------------------------------------------------- k_cvtx
__global__ __launch_bounds__(256) void k_cvtx(const float* __restrict__ x,
                                              ushort* __restrict__ xh,
                                              ushort* __restrict__ xl)
{
  const int i = (blockIdx.x * 256 + threadIdx.x) * 4;
  const float4 v = *(const float4*)&x[i];
  ushort4 h, l;
  h.x = f2bf(v.x); l.x = f2bf(v.x - bf2f(h.x));
  h.y = f2bf(v.y); l.y = f2bf(v.y - bf2f(h.y));
  h.z = f2bf(v.z); l.z = f2bf(v.z - bf2f(h.z));
  h.w = f2bf(v.w); l.w = f2bf(v.w - bf2f(h.w));
  *(ushort4*)&xh[i] = h;
  *(ushort4*)&xl[i] = l;
}

// ---------------------------------------------------------------- k_mm
__global__ __launch_bounds__(256) void k_mm(
    const ushort* __restrict__ Ah, const ushort* __restrict__ Al,
    const ushort* __restrict__ Bh, const ushort* __restrict__ Bl,
    float* __restrict__ Y, int N, int K)
{
  __shared__ __align__(16) ushort Ahs[128][40];
  __shared__ __align__(16) ushort Als[128][40];
  __shared__ __align__(16) ushort Bhs[128][40];
  __shared__ __align__(16) ushort Bls[128][40];
  const int tid = threadIdx.x;
  const int m0 = blockIdx.x * 128, n0 = blockIdx.y * 128;
  const int w = tid >> 6, lane = tid & 63;
  const int wm = (w & 1) * 64, wn = (w >> 1) * 64;
  const int fr = lane & 15, fg = lane >> 4;

  f32x4 acc[4][4];
#pragma unroll
  for (int i = 0; i < 4; ++i)
#pragma unroll
    for (int j = 0; j < 4; ++j) acc[i][j] = (f32x4){0.f, 0.f, 0.f, 0.f};

  const int sr = tid >> 1, sk = (tid & 1) * 16;
  const ushort* agh = Ah + (size_t)(m0 + sr) * K + sk;
  const ushort* agl = Al + (size_t)(m0 + sr) * K + sk;
  const ushort* bgh = Bh + (size_t)(n0 + sr) * K + sk;
  const ushort* bgl = Bl + (size_t)(n0 + sr) * K + sk;
  short8 pah0 = *(const short8*)agh, pah1 = *(const short8*)(agh + 8);
  short8 pal0 = *(const short8*)agl, pal1 = *(const short8*)(agl + 8);
  short8 pbh0 = *(const short8*)bgh, pbh1 = *(const short8*)(bgh + 8);
  short8 pbl0 = *(const short8*)bgl, pbl1 = *(const short8*)(bgl + 8);

  const int NT = K >> 5;
  for (int kt = 0; kt < NT; ++kt) {
    __syncthreads();
    *(short8*)&Ahs[sr][sk] = pah0; *(short8*)&Ahs[sr][sk + 8] = pah1;
    *(short8*)&Als[sr][sk] = pal0; *(short8*)&Als[sr][sk + 8] = pal1;
    *(short8*)&Bhs[sr][sk] = pbh0; *(short8*)&Bhs[sr][sk + 8] = pbh1;
    *(short8*)&Bls[sr][sk] = pbl0; *(short8*)&Bls[sr][sk + 8] = pbl1;
    __syncthreads();
    if (kt + 1 < NT) {
      const size_t off = (size_t)(kt + 1) * 32;
      pah0 = *(const short8*)(agh + off); pah1 = *(const short8*)(agh + off + 8);
      pal0 = *(const short8*)(agl + off); pal1 = *(const short8*)(agl + off + 8);
      pbh0 = *(const short8*)(bgh + off); pbh1 = *(const short8*)(bgh + off + 8);
      pbl0 = *(const short8*)(bgl + off); pbl1 = *(const short8*)(bgl + off + 8);
    }
    short8 fah[4], fal[4], fbh[4], fbl[4];
#pragma unroll
    for (int i = 0; i < 4; ++i) {
      fah[i] = *(const short8*)&Ahs[wm + i * 16 + fr][fg * 8];
      fal[i] = *(const short8*)&Als[wm + i * 16 + fr][fg * 8];
    }
#pragma unroll
    for (int j = 0; j < 4; ++j) {
      fbh[j] = *(const short8*)&Bhs[wn + j * 16 + fr][fg * 8];
      fbl[j] = *(const short8*)&Bls[wn + j * 16 + fr][fg * 8];
    }
#pragma unroll
    for (int i = 0; i < 4; ++i)
#pragma unroll
      for (int j = 0; j < 4; ++j) {
        f32x4 t = MFMA(fah[i], fbh[j], acc[i][j]);
        t = MFMA(fal[i], fbh[j], t);
        t = MFMA(fah[i], fbl[j], t);
        acc[i][j] = t;
      }
  }

  const int rb = fg * 4;
#pragma unroll
  for (int i = 0; i < 4; ++i)
#pragma unroll
    for (int j = 0; j < 4; ++j) {
      const int n = n0 + wn + j * 16 + fr;
#pragma unroll
      for (int r = 0; r < 4; ++r) {
        const int m = m0 + wm + i * 16 + rb + r;
        Y[(size_t)m * N + n] = acc[i][j][r];
      }
    }
}

// ---------------------------------------------------------------- k_fin
__global__ __launch_bounds__(256) void k_fin(
    const ushort* __restrict__ A, const ushort* __restrict__ Bt,
    const float* __restrict__ b_vo, const float* __restrict__ b_ao,
    float* __restrict__ out)
{
  __shared__ __align__(16) ushort As[128][40];
  __shared__ __align__(16) ushort Bs[128][40];
  const int tid = threadIdx.x;
  const int m0 = blockIdx.x * 128, n0 = blockIdx.y * 128;
  const int w = tid >> 6, lane = tid & 63;
  const int wm = (w & 1) * 64, wn = (w >> 1) * 64;
  const int fr = lane & 15, fg = lane >> 4;
  const int K = KF;

  f32x4 acc[4][4];
#pragma unroll
  for (int i = 0; i < 4; ++i)
#pragma unroll
    for (int j = 0; j < 4; ++j) acc[i][j] = (f32x4){0.f, 0.f, 0.f, 0.f};

  const int sr = tid >> 1, sk = (tid & 1) * 16;
  const ushort* ag = A + (size_t)(m0 + sr) * K + sk;
  const ushort* bg = Bt + (size_t)(n0 + sr) * K + sk;
  short8 a0 = *(const short8*)ag;
  short8 a1 = *(const short8*)(ag + 8);
  short8 b0 = *(const short8*)bg;
  short8 b1 = *(const short8*)(bg + 8);

  const int NT = K >> 5;
  for (int kt = 0; kt < NT; ++kt) {
    __syncthreads();
    *(short8*)&As[sr][sk] = a0; *(short8*)&As[sr][sk + 8] = a1;
    *(short8*)&Bs[sr][sk] = b0; *(short8*)&Bs[sr][sk + 8] = b1;
    __syncthreads();
    if (kt + 1 < NT) {
      const ushort* agn = ag + (size_t)(kt + 1) * 32;
      const ushort* bgn = bg + (size_t)(kt + 1) * 32;
      a0 = *(const short8*)agn; a1 = *(const short8*)(agn + 8);
      b0 = *(const short8*)bgn; b1 = *(const short8*)(bgn + 8);
    }
    short8 aF[4], bF[4];
#pragma unroll
    for (int i = 0; i < 4; ++i) aF[i] = *(const short8*)&As[wm + i * 16 + fr][fg * 8];
#pragma unroll
    for (int j = 0; j < 4; ++j) bF[j] = *(const short8*)&Bs[wn + j * 16 + fr][fg * 8];
#pragma unroll
    for (int i = 0; i < 4; ++i)
#pragma unroll
      for (int j = 0; j < 4; ++j)
        acc[i][j] = MFMA(aF[i], bF[j], acc[i][j]);
  }

  const int rb = fg * 4;
#pragma unroll
  for (int j = 0; j < 4; ++j) {
    const int n = n0 + wn + j * 16 + fr;
    const float bias = b_vo[n] + b_ao[n];
#pragma unroll
    for (int i = 0; i < 4; ++i)
#pragma unroll
      for (int r = 0; r < 4; ++r) {
        const int m = m0 + wm + i * 16 + rb + r;
        out[(size_t)m * ND + n] = acc[i][j][r] + bias;
      }
  }
}

// ---------------------------------------------------------------- k_rope
__global__ __launch_bounds__(256) void k_rope(
    const float* __restrict__ Y,
    ushort* __restrict__ qAh, ushort* __restrict__ qAl,
    ushort* __restrict__ kBh, ushort* __restrict__ kBl,
    ushort* __restrict__ Vt)
{
  __shared__ float t0[64][65];
  __shared__ float t1[64][72];
  const int tid = threadIdx.x;
  const int l0 = blockIdx.x * 64, h = blockIdx.y;
  const int b = l0 >> 10, ll0 = l0 & 1023;
  const int bh = b * NH + h;
  const int rr = tid >> 6, cc = tid & 63;
  const float inv = powf(10000.f, -(float)(cc & ~1) / 64.f);
  const bool odd = (cc & 1) != 0;

  // ---- q ----
  for (int p = 0; p < 16; ++p) {
    const int r = p * 4 + rr;
    t0[r][cc] = Y[(size_t)(l0 + r) * NCAT + h * 64 + cc];
  }
  __syncthreads();
  for (int p = 0; p < 16; ++p) {
    const int r = p * 4 + rr;
    float sv, cv;
    __sincosf((float)(ll0 + r) * inv, &sv, &cv);
    const float e = t0[r][cc & ~1], o = t0[r][(cc & ~1) + 1];
    const float val = (odd ? fmaf(e, sv, o * cv) : fmaf(e, cv, -o * sv)) * SCL_S;
    const size_t row = ((size_t)bh * NL + ll0 + r) * 128 + cc;
    const ushort hi = f2bf(val);
    qAh[row] = hi;
    qAl[row] = f2bf(val - bf2f(hi));
  }
  __syncthreads();
  // ---- k ----
  for (int p = 0; p < 16; ++p) {
    const int r = p * 4 + rr;
    t0[r][cc] = Y[(size_t)(l0 + r) * NCAT + 512 + h * 64 + cc];
  }
  __syncthreads();
  for (int p = 0; p < 16; ++p) {
    const int r = p * 4 + rr;
    float sv, cv;
    __sincosf((float)(ll0 + r) * inv, &sv, &cv);
    const float e = t0[r][cc & ~1], o = t0[r][(cc & ~1) + 1];
    const float val = odd ? fmaf(e, sv, o * cv) : fmaf(e, cv, -o * sv);
    const size_t row = ((size_t)bh * NL + ll0 + r) * 128 + cc;
    const ushort hi = f2bf(val);
    kBh[row] = hi;
    kBl[row] = f2bf(val - bf2f(hi));
  }
  // ---- v (transpose to Vt[dim][token]) ----
  for (int p = 0; p < 16; ++p) {
    const int r = p * 4 + rr;
    t1[cc][r] = Y[(size_t)(l0 + r) * NCAT + 1024 + h * 64 + cc];
  }
  __syncthreads();
  for (int p = 0; p < 16; ++p) {
    const int hd = p * 4 + rr;
    Vt[((size_t)bh * 112 + hd) * NL + ll0 + cc] = f2bf(t1[hd][cc]);
  }
  // zero Vt pad rows 103..111
  for (int u = tid; u < 9 * 64; u += 256)
    Vt[((size_t)bh * 112 + 103 + (u >> 6)) * NL + ll0 + (u & 63)] = 0;
}

// ---------------------------------------------------------------- k_rot
__global__ __launch_bounds__(256) void k_rot(
    const float* __restrict__ Y,
    const float* __restrict__ rots, const float* __restrict__ trans,
    const float* __restrict__ mask,
    const float* __restrict__ bvq, const float* __restrict__ bvk,
    const float* __restrict__ bvv, const float* __restrict__ baq,
    const float* __restrict__ bav,
    ushort* __restrict__ qAh, ushort* __restrict__ qAl,
    ushort* __restrict__ kBh, ushort* __restrict__ kBl,
    ushort* __restrict__ Vt,
    float* __restrict__ aq_t, float* __restrict__ penc)
{
  __shared__ float ys[8][912];
  const int tb = blockIdx.x * 8;
  const int b = tb >> 10;
  const int tid = threadIdx.x;

  for (int t = 0; t < 8; ++t)
    for (int n = tid; n < 912; n += 256)
      ys[t][n] = Y[(size_t)(tb + t) * NCAT + 1536 + n];
  __syncthreads();

  // vq -> qA cols 64..99 ; vk -> kB cols 64..99 ; vv -> Vt rows 64..99
  for (int u = tid; u < 8 * 288; u += 256) {
    const int t = u / 288, n = u % 288;
    const int l = tb + t, ll = l & (NL - 1);
    const int c = n % 3, base = n - c;
    const int h = n / NV3, m = n % NV3;
    const float r0 = rots[(size_t)l * 9 + c * 3 + 0];
    const float r1 = rots[(size_t)l * 9 + c * 3 + 1];
    const float r2 = rots[(size_t)l * 9 + c * 3 + 2];
    const float vqv = (r0 * (ys[t][base] + bvq[base])
                     + r1 * (ys[t][base + 1] + bvq[base + 1])
                     + r2 * (ys[t][base + 2] + bvq[base + 2])) * SCL_V;
    const float vkv = r0 * (ys[t][288 + base] + bvk[base])
                    + r1 * (ys[t][289 + base] + bvk[base + 1])
                    + r2 * (ys[t][290 + base] + bvk[base + 2]);
    const float vvv = r0 * (ys[t][576 + base] + bvv[base])
                    + r1 * (ys[t][577 + base] + bvv[base + 1])
                    + r2 * (ys[t][578 + base] + bvv[base + 2]);
    const size_t row = ((size_t)(b * NH + h) * NL + ll) * 128 + 64 + m;
    ushort hi = f2bf(vqv);
    qAh[row] = hi; qAl[row] = f2bf(vqv - bf2f(hi));
    hi = f2bf(vkv);
    kBh[row] = hi; kBl[row] = f2bf(vkv - bf2f(hi));
    Vt[((size_t)(b * NH + h) * 112 + 64 + m) * NL + ll] = f2bf(vvv);
  }
  // zero qA cols 100..127
  for (int u = tid; u < 8 * 8 * 14; u += 256) {
    const int t = u / 112, rem = u % 112, h = rem / 14, k = rem % 14;
    const int ll = (tb + t) & (NL - 1);
    const size_t row = ((size_t)(b * NH + h) * NL + ll) * 128 + 100 + 2 * k;
    *(uint*)&qAh[row] = 0;
    *(uint*)&qAl[row] = 0;
  }
  // aq (exact fp32, transposed) + zero kB pad cols 100..127
  for (int u = tid; u < 64; u += 256) {
    const int t = u >> 3, h = u & 7;
    const int l = tb + t, ll = l & (NL - 1);
    const int base = h * 3;
    const size_t tok = (size_t)(b * NH + h) * NL + ll;
#pragma unroll
    for (int c = 0; c < 3; ++c) {
      const float aqv =
          rots[(size_t)l * 9 + c * 3 + 0] * (ys[t][864 + base] + baq[base])
        + rots[(size_t)l * 9 + c * 3 + 1] * (ys[t][865 + base] + baq[base + 1])
        + rots[(size_t)l * 9 + c * 3 + 2] * (ys[t][866 + base] + baq[base + 2])
        + trans[(size_t)l * 3 + c];
      aq_t[((size_t)(b * NH + h) * 3 + c) * NL + ll] = aqv;
    }
#pragma unroll
    for (int k = 0; k < 14; ++k) {
      *(uint*)&kBh[tok * 128 + 100 + 2 * k] = 0;
      *(uint*)&kBl[tok * 128 + 100 + 2 * k] = 0;
    }
  }
  // av -> Vt rows 100..102
  for (int u = tid; u < 8 * 24; u += 256) {
    const int t = u / 24, n = u % 24;
    const int l = tb + t, ll = l & (NL - 1);
    const int c = n % 3, h = n / 3, base = h * 3;
    const float val = rots[(size_t)l * 9 + c * 3 + 0] * (ys[t][888 + base] + bav[base])
                    + rots[(size_t)l * 9 + c * 3 + 1] * (ys[t][889 + base] + bav[base + 1])
                    + rots[(size_t)l * 9 + c * 3 + 2] * (ys[t][890 + base] + bav[base + 2])
                    + trans[(size_t)l * 3 + c];
    Vt[((size_t)(b * NH + h) * 112 + 100 + c) * NL + ll] = f2bf(val);
  }
  // penalty
  for (int u = tid; u < 8; u += 256) {
    const int ll = (tb + u) & (NL - 1);
    penc[(size_t)b * NL + ll] = 1e6f * (1.0f - mask[(size_t)b * NL + ll]);
  }
}

// ---------------------------------------------------------------- k_attn
// Flash MFMA attention, 16 q-rows/block, 4 independent j-quarter waves.
// No barriers in the main loop (P_s is wave-private); 4-way combine at end.
__global__ __launch_bounds__(256) void k_attn(
    const ushort* __restrict__ qAh, const ushort* __restrict__ qAl,
    const ushort* __restrict__ kBh, const ushort* __restrict__ kBl,
    const ushort* __restrict__ Vt,
    const float* __restrict__ aq_t, const float* __restrict__ penc,
    const float* __restrict__ rots, const float* __restrict__ trans,
    const float* __restrict__ affw,
    ushort* __restrict__ catb)
{
  __shared__ __align__(16) ushort P_s[4][16][72];
  __shared__ float Ocmb[4][16][112];
  __shared__ float mst[4][16], lst[4][16];
  __shared__ float fac[4][16];
  __shared__ float linv[16];

  const int bh = blockIdx.y;
  const int b = bh >> 3, h = bh & 7;
  const int i0 = blockIdx.x * 16;
  const int tid = threadIdx.x;
  const int w = tid >> 6, lane = tid & 63;
  const int fr = lane & 15, fg = lane >> 4;

  const float spw = logf(1.0f + expf(affw[h]));

  // q fragments straight from global (once per wave)
  short8 aQh[4], aQl[4];
  const size_t qrow = ((size_t)bh * NL + i0 + fr) * 128;
#pragma unroll
  for (int ks = 0; ks < 4; ++ks) {
    aQh[ks] = *(const short8*)&qAh[qrow + ks * 32 + fg * 8];
    aQl[ks] = *(const short8*)&qAl[qrow + ks * 32 + fg * 8];
  }

  const float* aqx = aq_t + (size_t)bh * 3 * NL;
  float ai0[4], ai1[4], ai2[4];
#pragma unroll
  for (int r_ = 0; r_ < 4; ++r_) {
    const int row = i0 + fg * 4 + r_;
    ai0[r_] = aqx[row];
    ai1[r_] = aqx[NL + row];
    ai2[r_] = aqx[2 * NL + row];
  }

  float mrun[4], lrun[4];
#pragma unroll
  for (int r_ = 0; r_ < 4; ++r_) { mrun[r_] = -3.0e38f; lrun[r_] = 0.f; }

  f32x4 accO[7];
#pragma unroll
  for (int ct = 0; ct < 7; ++ct) accO[ct] = (f32x4){0.f, 0.f, 0.f, 0.f};

  const size_t kbase = (size_t)bh * NL * 128;
  const size_t vbase = (size_t)bh * 112 * NL;

  for (int jt = 0; jt < 4; ++jt) {
    const int j0 = w * 256 + jt * 64;

    f32x4 accS[4];
#pragma unroll
    for (int ct = 0; ct < 4; ++ct) accS[ct] = (f32x4){0.f, 0.f, 0.f, 0.f};
#pragma unroll
    for (int ct = 0; ct < 4; ++ct) {
      const size_t rowb = kbase + (size_t)(j0 + ct * 16 + fr) * 128;
#pragma unroll
      for (int ks = 0; ks < 4; ++ks) {
        const short8 bh8 = *(const short8*)&kBh[rowb + ks * 32 + fg * 8];
        const short8 bl8 = *(const short8*)&kBl[rowb + ks * 32 + fg * 8];
        f32x4 t = MFMA(aQh[ks], bh8, accS[ct]);
        t = MFMA(aQl[ks], bh8, t);
        t = MFMA(aQh[ks], bl8, t);
        accS[ct] = t;
      }
    }

    // exact fp32 distances + penalty, online softmax
    float pvals[4][4];
    float smax[4] = {-3.0e38f, -3.0e38f, -3.0e38f, -3.0e38f};
#pragma unroll
    for (int ct = 0; ct < 4; ++ct) {
      const int j = j0 + ct * 16 + fr;
      const float aj0 = aqx[j];
      const float aj1 = aqx[NL + j];
      const float aj2v = aqx[2 * NL + j];
      const float pen = penc[(size_t)b * NL + j];
#pragma unroll
      for (int r_ = 0; r_ < 4; ++r_) {
        const float dx = ai0[r_] - aj0;
        const float dy = ai1[r_] - aj1;
        const float dz = ai2[r_] - aj2v;
        const float s = accS[ct][r_]
                      - spw * sqrtf(dx * dx + dy * dy + dz * dz) - pen;
        pvals[ct][r_] = s;
        smax[r_] = fmaxf(smax[r_], s);
      }
    }
#pragma unroll
    for (int off = 1; off < 16; off <<= 1) {
#pragma unroll
      for (int r_ = 0; r_ < 4; ++r_)
        smax[r_] = fmaxf(smax[r_], __shfl_xor(smax[r_], off));
    }
    float scale[4], lsum[4];
#pragma unroll
    for (int r_ = 0; r_ < 4; ++r_) {
      const float mnew = fmaxf(mrun[r_], smax[r_]);
      scale[r_] = __expf(mrun[r_] - mnew);
      mrun[r_] = mnew;
      lsum[r_] = 0.f;
    }
#pragma unroll
    for (int ct = 0; ct < 4; ++ct)
#pragma unroll
      for (int r_ = 0; r_ < 4; ++r_) {
        const float p = __expf(pvals[ct][r_] - mrun[r_]);
        pvals[ct][r_] = p;
        lsum[r_] += p;
      }
#pragma unroll
    for (int off = 1; off < 16; off <<= 1) {
#pragma unroll
      for (int r_ = 0; r_ < 4; ++r_) lsum[r_] += __shfl_xor(lsum[r_], off);
    }
#pragma unroll
    for (int r_ = 0; r_ < 4; ++r_) lrun[r_] = lrun[r_] * scale[r_] + lsum[r_];
#pragma unroll
    for (int ct = 0; ct < 7; ++ct)
#pragma unroll
      for (int r_ = 0; r_ < 4; ++r_) accO[ct][r_] *= scale[r_];

    // P tile to this wave's private LDS region (same-wave ordering via lgkmcnt)
#pragma unroll
    for (int ct = 0; ct < 4; ++ct)
#pragma unroll
      for (int r_ = 0; r_ < 4; ++r_)
        P_s[w][fg * 4 + r_][ct * 16 + fr] = f2bf(pvals[ct][r_]);

    const short8 aP0 = *(const short8*)&P_s[w][fr][fg * 8];
    const short8 aP1 = *(const short8*)&P_s[w][fr][32 + fg * 8];
#pragma unroll
    for (int ct = 0; ct < 7; ++ct) {
      const size_t vrow = vbase + (size_t)(ct * 16 + fr) * NL + j0;
      const short8 b0 = *(const short8*)&Vt[vrow + fg * 8];
      const short8 b1 = *(const short8*)&Vt[vrow + 32 + fg * 8];
      f32x4 t = MFMA(aP0, b0, accO[ct]);
      accO[ct] = MFMA(aP1, b1, t);
    }
  }

  // publish partials
#pragma unroll
  for (int ct = 0; ct < 7; ++ct)
#pragma unroll
    for (int r_ = 0; r_ < 4; ++r_)
      Ocmb[w][fg * 4 + r_][ct * 16 + fr] = accO[ct][r_];
  if (fr == 0) {
#pragma unroll
    for (int r_ = 0; r_ < 4; ++r_) {
      mst[w][fg * 4 + r_] = mrun[r_];
      lst[w][fg * 4 + r_] = lrun[r_];
    }
  }
  __syncthreads();

  // per-row combine factors
  if (tid < 16) {
    const float m0 = mst[0][tid], m1 = mst[1][tid];
    const float m2 = mst[2][tid], m3 = mst[3][tid];
    const float M = fmaxf(fmaxf(m0, m1), fmaxf(m2, m3));
    const float e0 = __expf(m0 - M), e1 = __expf(m1 - M);
    const float e2 = __expf(m2 - M), e3 = __expf(m3 - M);
    const float L = lst[0][tid] * e0 + lst[1][tid] * e1
                  + lst[2][tid] * e2 + lst[3][tid] * e3;
    fac[0][tid] = e0; fac[1][tid] = e1; fac[2][tid] = e2; fac[3][tid] = e3;
    linv[tid] = 1.0f / L;
  }
  __syncthreads();

  // combine into Ocmb[0]
  for (int u = tid; u < 16 * 112; u += 256) {
    const int row = u / 112, d = u % 112;
    const float val = (Ocmb[0][row][d] * fac[0][row]
                     + Ocmb[1][row][d] * fac[1][row]
                     + Ocmb[2][row][d] * fac[2][row]
                     + Ocmb[3][row][d] * fac[3][row]) * linv[row];
    Ocmb[0][row][d] = val;
  }
  __syncthreads();

  // epilogue: rotations + catb writes
  for (int u = tid; u < 16 * 103; u += 256) {
    const int lr = u / 103, d = u % 103;
    const int gi = i0 + lr;
    const size_t gl = (size_t)b * NL + gi;
    const float* O = Ocmb[0][lr];
    float val;
    int col;
    if (d < 64) {
      val = O[d];
      col = h * 64 + d;
    } else if (d < 100) {
      const int v3 = d - 64;
      const int n = v3 % 3;
      const int base = 64 + v3 - n;
      val = O[base] * rots[gl * 9 + n] + O[base + 1] * rots[gl * 9 + 3 + n]
          + O[base + 2] * rots[gl * 9 + 6 + n];
      col = 512 + h * NV3 + v3;
    } else {
      const int n = d - 100;
      const float c0 = O[100] - trans[gl * 3 + 0];
      const float c1 = O[101] - trans[gl * 3 + 1];
      const float c2 = O[102] - trans[gl * 3 + 2];
      val = c0 * rots[gl * 9 + n] + c1 * rots[gl * 9 + 3 + n] + c2 * rots[gl * 9 + 6 + n];
      col = 800 + h * 3 + n;
    }
    catb[gl * KF + col] = f2bf(val);
  }
  if (h == 0) {
    for (int u = tid; u < 16 * 8; u += 256)
      catb[((size_t)b * NL + i0 + (u >> 3)) * KF + 824 + (u & 7)] = 0;
  }
}

} // namespace

extern "C" void kernel_launch(void* const* d_in, const int* in_sizes, int n_in,
                              void* d_out, int out_size, void* d_ws, size_t ws_size,
                              hipStream_t stream)
{
  const float* x       = (const float*)d_in[0];
  const float* mask    = (const float*)d_in[1];
  const float* rots    = (const float*)d_in[2];
  const float* trans   = (const float*)d_in[3];
  const float* w_q     = (const float*)d_in[4];
  const float* w_k     = (const float*)d_in[5];
  const float* w_v     = (const float*)d_in[6];
  const float* w_o     = (const float*)d_in[7];
  const float* w_vq_w  = (const float*)d_in[8];
  const float* w_vq_b  = (const float*)d_in[9];
  const float* w_vk_w  = (const float*)d_in[10];
  const float* w_vk_b  = (const float*)d_in[11];
  const float* w_vv_w  = (const float*)d_in[12];
  const float* w_vv_b  = (const float*)d_in[13];
  const float* w_vo_w  = (const float*)d_in[14];
  const float* w_vo_b  = (const float*)d_in[15];
  const float* w_aq_w  = (const float*)d_in[16];
  const float* w_aq_b  = (const float*)d_in[17];
  const float* w_av_w  = (const float*)d_in[18];
  const float* w_av_b  = (const float*)d_in[19];
  const float* w_ao_w  = (const float*)d_in[20];
  const float* w_ao_b  = (const float*)d_in[21];
  const float* aff_w   = (const float*)d_in[22];
  float* out = (float*)d_out;

  // workspace (~41.4 MiB), aliased:
  //  region A (9.44 MB): xh|xl|wch|wcl (k_mm inputs) -> qAh|qAl|aq_t after k_mm
  //  Y (21 MB): projections -> catb (3.4 MB) overlays after k_rope/k_rot
  char* base = (char*)d_ws;
  ushort* xh  = (ushort*)base;
  ushort* xl  = xh + (size_t)2048 * 512;
  ushort* wch = xl + (size_t)2048 * 512;
  ushort* wcl = wch + (size_t)2560 * 512;
  ushort* qAh = (ushort*)base;                       // 4 MB
  ushort* qAl = qAh + (size_t)16 * 1024 * 128;       // 4 MB
  float*  aq_t = (float*)(qAl + (size_t)16 * 1024 * 128);  // 196 KB
  char* p = base + 9437184;
  ushort* wcat2 = (ushort*)p; p += (size_t)512 * 832 * 2;
  float*  Y     = (float*)p;
  ushort* catb  = (ushort*)Y;
  p += (size_t)2048 * 2560 * 4;
  ushort* kBh = (ushort*)p; p += (size_t)16 * 1024 * 128 * 2;
  ushort* kBl = (ushort*)p; p += (size_t)16 * 1024 * 128 * 2;
  ushort* Vt  = (ushort*)p; p += (size_t)16 * 112 * 1024 * 2;
  float* penc = (float*)p;  p += (size_t)2048 * 4;

  k_pack<<<dim3(40, 13, 2), 256, 0, stream>>>(w_q, w_k, w_v, w_vq_w, w_vk_w,
                                              w_vv_w, w_aq_w, w_av_w,
                                              w_o, w_vo_w, w_ao_w,
                                              wch, wcl, wcat2);
  k_cvtx<<<1024, 256, 0, stream>>>(x, xh, xl);
  k_mm<<<dim3(16, 20), 256, 0, stream>>>(xh, xl, wch, wcl, Y, NCAT, 512);
  k_rope<<<dim3(32, 8), 256, 0, stream>>>(Y, qAh, qAl, kBh, kBl, Vt);
  k_rot<<<256, 256, 0, stream>>>(Y, rots, trans, mask,
                                 w_vq_b, w_vk_b, w_vv_b, w_aq_b, w_av_b,
                                 qAh, qAl, kBh, kBl, Vt, aq_t, penc);
  k_attn<<<dim3(64, 16), 256, 0, stream>>>(qAh, qAl, kBh, kBl, Vt,
                                           aq_t, penc, rots, trans, aff_w, catb);
  k_fin<<<dim3(16, 4), 256, 0, stream>>>(catb, wcat2, w_vo_b, w_ao_b, out);
}